// Round 15
// baseline (387.656 us; speedup 1.0000x reference)
//
#include <hip/hip_runtime.h>
#include <hip/hip_bf16.h>

// ---------------------------------------------------------------------------
// Model: B=8 S=1024 D=256 H=8 DK=64 DV=256; LB=LF=32, CUT=128, VOCAB=240
// R14 base (375.7us) + 3-deep counted-vmcnt pipeline in BOTH GEMM kernels
// (same validated pattern as the attn kernels: per-wave counted vmcnt +
// raw s_barrier, never vmcnt(0) mid-loop).
// ---------------------------------------------------------------------------

typedef __bf16 bf16_t;
typedef __bf16 bf16x4 __attribute__((ext_vector_type(4)));
typedef __bf16 bf16x8 __attribute__((ext_vector_type(8)));
typedef float f32x4 __attribute__((ext_vector_type(4)));

__device__ __forceinline__ f32x4 mfma16(bf16x8 a, bf16x8 b, f32x4 c) {
  return __builtin_amdgcn_mfma_f32_16x16x32_bf16(a, b, c, 0, 0, 0);
}

#define GLL16(GP, LP)                                                          \
  __builtin_amdgcn_global_load_lds(                                            \
      (const __attribute__((address_space(1))) void*)(GP),                     \
      (__attribute__((address_space(3))) void*)(LP), 16, 0, 0)

__device__ __forceinline__ int imin(int a, int b) { return a < b ? a : b; }
__device__ __forceinline__ int imax(int a, int b) { return a > b ? a : b; }

// ---- all weight transposes+casts in one launch -----------------------------
struct WEnt { const float* src; bf16_t* dst; int K; int N; };
struct WPack { WEnt e[13]; };

__global__ void wcast_all(WPack p) {
  const WEnt E = p.e[blockIdx.y];
  const int tot = E.K * E.N;
  for (int id = blockIdx.x * 256 + threadIdx.x; id < tot; id += gridDim.x * 256) {
    int n = id / E.K, k = id - n * E.K;
    E.dst[id] = (bf16_t)E.src[(size_t)k * E.N + n];
  }
}

__global__ void embed_k(const int* __restrict__ xs, const float* __restrict__ emb,
                        bf16_t* __restrict__ x) {
  int row = blockIdx.x, d = threadIdx.x;
  int tok = xs[row];
  x[(size_t)row * 256 + d] = (bf16_t)emb[(size_t)tok * 256 + d];
}

__global__ void sentinel_k(float* out) { out[0] = 1.0e6f; }

// ---- GEMM 128x128, 3-deep counted-vmcnt pipeline ---------------------------
// VT mode: columns c>=1024 (v-slice of fused qkv) are written TRANSPOSED into
// vt[b*2048 + (c-1024)][s] instead of C (fuses the V transpose).
template <bool F32OUT, bool VT>
__global__ __launch_bounds__(256) void gemm_bt(
    const bf16_t* __restrict__ A, int lda, const bf16_t* __restrict__ Bt, int K,
    void* __restrict__ Cv, int ldc, const float* __restrict__ bias, int N,
    bf16_t* __restrict__ vt) {
  __shared__ bf16_t As[3][128 * 32];
  __shared__ bf16_t Bs[3][128 * 32];
  const int tid = threadIdx.x;
  const int lane = tid & 63, wave = tid >> 6;
  const int wr = wave >> 1, wc = wave & 1;
  const int lr = lane & 15, lg = lane >> 4;
  const int bm = blockIdx.y, bn = blockIdx.x;

  const int ar = tid >> 2;
  const int ac = (tid & 3) * 8;
  const bf16_t* a0 = A + (size_t)(bm * 128 + ar) * lda + ac;
  const bf16_t* a1 = A + (size_t)(bm * 128 + 64 + ar) * lda + ac;
  int br0 = imin(bn * 128 + ar, N - 1);
  int br1 = imin(bn * 128 + 64 + ar, N - 1);
  const bf16_t* b0 = Bt + (size_t)br0 * K + ac;
  const bf16_t* b1 = Bt + (size_t)br1 * K + ac;

  f32x4 acc[4][4] = {};
  const int nk = K >> 5;

  auto STAGE = [&](int kt, int bs) {
    const int ko = kt * 32;
    GLL16(a0 + ko, &As[bs][wave * 512]);
    GLL16(a1 + ko, &As[bs][2048 + wave * 512]);
    GLL16(b0 + ko, &Bs[bs][wave * 512]);
    GLL16(b1 + ko, &Bs[bs][2048 + wave * 512]);
  };

  STAGE(0, 0);
  if (nk > 1) STAGE(1, 1);
  for (int kt = 0; kt < nk; ++kt) {
    const int buf = kt % 3;
    if (kt + 1 < nk) {
      asm volatile("s_waitcnt vmcnt(4)" ::: "memory");
    } else {
      asm volatile("s_waitcnt vmcnt(0)" ::: "memory");
    }
    __builtin_amdgcn_s_barrier();
    if (kt + 2 < nk) STAGE(kt + 2, (kt + 2) % 3);
    bf16x8 af[4], bfv[4];
#pragma unroll
    for (int m = 0; m < 4; ++m)
      af[m] = *(const bf16x8*)&As[buf][(wr * 64 + m * 16 + lr) * 32 + lg * 8];
#pragma unroll
    for (int n = 0; n < 4; ++n)
      bfv[n] = *(const bf16x8*)&Bs[buf][(wc * 64 + n * 16 + lr) * 32 + lg * 8];
    __builtin_amdgcn_s_setprio(1);
#pragma unroll
    for (int m = 0; m < 4; ++m)
#pragma unroll
      for (int n = 0; n < 4; ++n) acc[m][n] = mfma16(af[m], bfv[n], acc[m][n]);
    __builtin_amdgcn_s_setprio(0);
  }
  const int r0 = bm * 128 + wr * 64;
  const int c0 = bn * 128 + wc * 64;
  if (VT && c0 >= 1024) {
    const int bq = r0 >> 10;
    const int s0 = r0 & 1023;
#pragma unroll
    for (int m = 0; m < 4; ++m)
#pragma unroll
      for (int n = 0; n < 4; ++n) {
        int c = c0 + n * 16 + lr;
        bf16x4 pk;
#pragma unroll
        for (int i = 0; i < 4; ++i) pk[i] = (bf16_t)acc[m][n][i];
        *(bf16x4*)(vt + (size_t)(bq * 2048 + (c - 1024)) * 1024 + s0 + m * 16 +
                   lg * 4) = pk;
      }
  } else {
#pragma unroll
    for (int m = 0; m < 4; ++m)
#pragma unroll
      for (int n = 0; n < 4; ++n) {
        int c = c0 + n * 16 + lr;
        if (c >= N) continue;
#pragma unroll
        for (int i = 0; i < 4; ++i) {
          int r = r0 + m * 16 + lg * 4 + i;
          if (F32OUT)
            ((float*)Cv)[(size_t)r * ldc + c] = acc[m][n][i] + bias[c];
          else
            ((bf16_t*)Cv)[(size_t)r * ldc + c] = (bf16_t)acc[m][n][i];
        }
      }
  }
}

// ---- GEMM BMx128, 3-deep pipeline, swapped operands ------------------------
// BM=32: waves 0-1 stage 3 loads/tile (A+2B), waves 2-3 stage 2 (2B) ->
// wave-uniform split counted wait.
template <int BM, bool F32OUT>
__global__ __launch_bounds__(256) void gemm_btm(
    const bf16_t* __restrict__ A, int lda, const bf16_t* __restrict__ Bt, int K,
    void* __restrict__ Cv, int ldc, const float* __restrict__ bias, int N) {
  constexpr int MF = BM / 32;
  __shared__ bf16_t As[3][BM * 32];
  __shared__ bf16_t Bs[3][128 * 32];
  const int tid = threadIdx.x;
  const int lane = tid & 63, wave = tid >> 6;
  const int wr = wave >> 1, wc = wave & 1;
  const int lr = lane & 15, lg = lane >> 4;
  const int bm = blockIdx.y, bn = blockIdx.x;

  const int ar = tid >> 2;
  const int ac = (tid & 3) * 8;
  const bf16_t* a0 = A + (size_t)(bm * BM + (BM == 32 ? (ar & 31) : ar)) * lda + ac;
  int br0 = imin(bn * 128 + ar, N - 1);
  int br1 = imin(bn * 128 + 64 + ar, N - 1);
  const bf16_t* b0 = Bt + (size_t)br0 * K + ac;
  const bf16_t* b1 = Bt + (size_t)br1 * K + ac;

  f32x4 acc[MF][4] = {};
  const int nk = K >> 5;

  auto STAGE = [&](int kt, int bs) {
    const int ko = kt * 32;
    if (BM == 64) {
      GLL16(a0 + ko, &As[bs][wave * 512]);
    } else {
      if (wave < 2) GLL16(a0 + ko, &As[bs][wave * 512]);
    }
    GLL16(b0 + ko, &Bs[bs][wave * 512]);
    GLL16(b1 + ko, &Bs[bs][2048 + wave * 512]);
  };

  STAGE(0, 0);
  if (nk > 1) STAGE(1, 1);
  for (int kt = 0; kt < nk; ++kt) {
    const int buf = kt % 3;
    if (kt + 1 < nk) {
      if (BM == 64 || wave < 2) {
        asm volatile("s_waitcnt vmcnt(3)" ::: "memory");
      } else {
        asm volatile("s_waitcnt vmcnt(2)" ::: "memory");
      }
    } else {
      asm volatile("s_waitcnt vmcnt(0)" ::: "memory");
    }
    __builtin_amdgcn_s_barrier();
    if (kt + 2 < nk) STAGE(kt + 2, (kt + 2) % 3);
    bf16x8 af[MF], bfv[4];
#pragma unroll
    for (int m = 0; m < MF; ++m)
      af[m] = *(const bf16x8*)&As[buf][(wr * (BM / 2) + m * 16 + lr) * 32 + lg * 8];
#pragma unroll
    for (int n = 0; n < 4; ++n)
      bfv[n] = *(const bf16x8*)&Bs[buf][(wc * 64 + n * 16 + lr) * 32 + lg * 8];
    __builtin_amdgcn_s_setprio(1);
#pragma unroll
    for (int m = 0; m < MF; ++m)
#pragma unroll
      for (int n = 0; n < 4; ++n) acc[m][n] = mfma16(bfv[n], af[m], acc[m][n]);
    __builtin_amdgcn_s_setprio(0);
  }
  const int r0 = bm * BM + wr * (BM / 2);
  const int c0 = bn * 128 + wc * 64;
#pragma unroll
  for (int m = 0; m < MF; ++m) {
    const int r = r0 + m * 16 + lr;
#pragma unroll
    for (int n = 0; n < 4; ++n) {
      const int c = c0 + n * 16 + lg * 4;
      if (c >= N) continue;
      if (F32OUT) {
        float4 bv = *(const float4*)&bias[c];
        float4 ov = {acc[m][n][0] + bv.x, acc[m][n][1] + bv.y,
                     acc[m][n][2] + bv.z, acc[m][n][3] + bv.w};
        *(float4*)&((float*)Cv)[(size_t)r * ldc + c] = ov;
      } else {
        bf16x4 pk;
#pragma unroll
        for (int i = 0; i < 4; ++i) pk[i] = (bf16_t)acc[m][n][i];
        *(bf16x4*)&((bf16_t*)Cv)[(size_t)r * ldc + c] = pk;
      }
    }
  }
}

// ---- fused flash attention QBLK=128 — LOCAL / CAUSAL (3-deep pipeline) -----
template <int VAR>
__global__ __launch_bounds__(512) void attn_k(
    const bf16_t* __restrict__ qkv, const bf16_t* __restrict__ vt,
    const float* __restrict__ bias, bf16_t* __restrict__ o, int ldqk, int ldo) {
  constexpr int S = 1024, H = 8;
  __shared__ bf16_t Klds[3][64 * 64];
  __shared__ bf16_t Vlds[3][256 * 64];
  __shared__ bf16_t Plds[8][16 * 64];
  __shared__ float blds[260];
  const int tid = threadIdx.x, lane = tid & 63, w = tid >> 6;
  const int lr = lane & 15, lg = lane >> 4;
  const int bh = blockIdx.x;
  const int qt = (VAR == 2) ? (7 - (int)blockIdx.y) : blockIdx.y;  // LPT
  const int b = bh >> 3, h = bh & 7;
  const int TSIZE = (VAR == 0) ? 65 : 257;
  for (int t = tid; t < TSIZE; t += 512) blds[t] = bias[t * H + h];
  const int qb0 = qt * 128;
#define QROW(j) (VAR == 2 ? qb0 + (j) * 8 + w : qb0 + w * 16 + (j))
  const size_t qoff = (size_t)(b * S + QROW(lr)) * ldqk + h * 64;
  bf16x8 qf0 = *(const bf16x8*)(qkv + qoff + lg * 8);
  bf16x8 qf1 = *(const bf16x8*)(qkv + qoff + 32 + lg * 8);
  int qr[4];
#pragma unroll
  for (int i = 0; i < 4; ++i) qr[i] = QROW(lg * 4 + i);

  f32x4 acc[16] = {};
  float m0[4], l0[4];
#pragma unroll
  for (int i = 0; i < 4; ++i) { m0[i] = -__builtin_inff(); l0[i] = 0.f; }
  int kt0 = 0, kt1 = 15;
  if (VAR == 0) {
    kt0 = imax(0, (qb0 - 32) >> 6);
    kt1 = imin(15, (qb0 + 127 + 32) >> 6);
  }
  if (VAR == 2) kt1 = 2 * qt + 1;

  const int sr = tid >> 3, sj = tid & 7;
  const int ksw = (sj ^ (sr & 7)) << 3;
  const bf16_t* kbase = qkv + 512 + (size_t)(b * S + sr) * ldqk + h * 64 + ksw;
  const bf16_t* vbase = vt + (size_t)((b * H + h) * 256 + sr) * 1024 + ksw;
  bf16_t* Pw = &Plds[w][0];

  auto STAGE = [&](int kt, int bs) {
    GLL16(kbase + (size_t)(kt * 64) * ldqk, &Klds[bs][w * 512]);
#pragma unroll
    for (int qq = 0; qq < 4; ++qq)
      GLL16(vbase + (size_t)(qq * 64) * 1024 + kt * 64,
            &Vlds[bs][qq * 4096 + w * 512]);
  };

  STAGE(kt0, 0);
  if (kt0 + 1 <= kt1) STAGE(kt0 + 1, 1);

  for (int kt = kt0; kt <= kt1; ++kt) {
    const int buf = (kt - kt0) % 3;
    if (kt < kt1) {
      asm volatile("s_waitcnt vmcnt(5)" ::: "memory");
    } else {
      asm volatile("s_waitcnt vmcnt(0)" ::: "memory");
    }
    __builtin_amdgcn_s_barrier();
    if (kt + 2 <= kt1) STAGE(kt + 2, (kt + 2 - kt0) % 3);

    const int kvlo = kt * 64;
    bool active = true;
    if (VAR == 0) {
      int q0w = qb0 + w * 16;
      active = (kvlo + 63 >= q0w - 32) && (kvlo <= q0w + 47);
    }
    if (VAR == 2) active = (kvlo <= qb0 + 120 + w);
    if (active) {
      f32x4 sf[4];
      __builtin_amdgcn_s_setprio(1);
#pragma unroll
      for (int n = 0; n < 4; ++n) {
        const int R = n * 16 + lr, rs = lr & 7;
        bf16x8 kb0 = *(const bf16x8*)&Klds[buf][R * 64 + ((lg ^ rs) << 3)];
        bf16x8 kb1 = *(const bf16x8*)&Klds[buf][R * 64 + (((4 + lg) ^ rs) << 3)];
        f32x4 z = {0.f, 0.f, 0.f, 0.f};
        z = mfma16(qf0, kb0, z);
        z = mfma16(qf1, kb1, z);
        sf[n] = z;
      }
      __builtin_amdgcn_s_setprio(0);
      bool sat = false;
      float cb = 0.f;
      if (VAR == 2) {
        if (kvlo + 63 <= qb0 - 128) { sat = true; cb = blds[0]; }
      }
      float tmL[4];
#pragma unroll
      for (int i = 0; i < 4; ++i) tmL[i] = -__builtin_inff();
      if (sat) {
#pragma unroll
        for (int n = 0; n < 4; ++n)
#pragma unroll
          for (int i = 0; i < 4; ++i) {
            float val = sf[n][i] * 0.125f + cb;
            sf[n][i] = val;
            tmL[i] = fmaxf(tmL[i], val);
          }
      } else {
#pragma unroll
        for (int n = 0; n < 4; ++n) {
          int kv = kvlo + n * 16 + lr;
#pragma unroll
          for (int i = 0; i < 4; ++i) {
            int rel = kv - qr[i];
            float val;
            if (VAR == 0) {
              val = (rel >= -32 && rel <= 32)
                        ? sf[n][i] * 0.125f + blds[rel + 32] : -1e9f;
            } else {
              int idx = imax(rel, -128) + 128;
              val = (rel <= 0) ? sf[n][i] * 0.125f + blds[idx] : -1e9f;
            }
            sf[n][i] = val;
            tmL[i] = fmaxf(tmL[i], val);
          }
        }
      }
      bool need = false;
#pragma unroll
      for (int i = 0; i < 4; ++i) need |= (tmL[i] > m0[i] + 8.0f);
      if (__any(need ? 1 : 0)) {
        float corr[4];
#pragma unroll
        for (int i = 0; i < 4; ++i) {
          float tm = tmL[i];
#pragma unroll
          for (int off = 1; off < 16; off <<= 1)
            tm = fmaxf(tm, __shfl_xor(tm, off));
          float nm = fmaxf(m0[i], tm);
          corr[i] = __expf(m0[i] - nm);
          m0[i] = nm;
          l0[i] *= corr[i];
        }
        f32x4 cv = {corr[0], corr[1], corr[2], corr[3]};
#pragma unroll
        for (int nf = 0; nf < 16; ++nf) acc[nf] *= cv;
      }
#pragma unroll
      for (int n = 0; n < 4; ++n)
#pragma unroll
        for (int i = 0; i < 4; ++i) {
          float p = __expf(sf[n][i] - m0[i]);
          sf[n][i] = p;
          l0[i] += p;
        }
#pragma unroll
      for (int n = 0; n < 4; ++n)
#pragma unroll
        for (int i = 0; i < 4; ++i) {
          int r = lg * 4 + i, cb2 = n * 16 + lr;
          Pw[r * 64 + (((cb2 >> 3) ^ (r & 7)) << 3) + (cb2 & 7)] =
              (bf16_t)sf[n][i];
        }
      __builtin_amdgcn_s_setprio(1);
#pragma unroll
      for (int c = 0; c < 2; ++c) {
        bf16x8 pa = *(const bf16x8*)&Pw[lr * 64 + (((c * 4 + lg) ^ (lr & 7)) << 3)];
#pragma unroll
        for (int nf = 0; nf < 16; ++nf) {
          const int R = nf * 16 + lr;
          bf16x8 vb = *(const bf16x8*)&Vlds[buf][R * 64 + (((c * 4 + lg) ^ (lr & 7)) << 3)];
          acc[nf] = mfma16(pa, vb, acc[nf]);
        }
      }
      __builtin_amdgcn_s_setprio(0);
    }
  }
  float rcp[4];
#pragma unroll
  for (int i = 0; i < 4; ++i) {
    float l = l0[i];
#pragma unroll
    for (int off = 1; off < 16; off <<= 1) l += __shfl_xor(l, off);
    rcp[i] = 1.f / l;
  }
#pragma unroll
  for (int nf = 0; nf < 16; ++nf)
#pragma unroll
    for (int i = 0; i < 4; ++i)
      o[(size_t)(b * S + qr[i]) * ldo + h * 256 + nf * 16 + lr] =
          (bf16_t)(acc[nf][i] * rcp[i]);
#undef QROW
}

// ---- fused flash attention QBLK=256 — GLOBAL (3-deep pipeline) -------------
__global__ __launch_bounds__(512) void attn_g256(
    const bf16_t* __restrict__ qkv, const bf16_t* __restrict__ vt,
    const float* __restrict__ bias, bf16_t* __restrict__ o, int ldqk, int ldo) {
  constexpr int S = 1024, H = 8;
  __shared__ bf16_t Klds[3][64 * 64];
  __shared__ bf16_t Vlds[3][256 * 64];
  __shared__ bf16_t Plds[8][2][16 * 64];
  __shared__ float blds[260];
  const int tid = threadIdx.x, lane = tid & 63, w = tid >> 6;
  const int lr = lane & 15, lg = lane >> 4;
  const int bh = blockIdx.x, qt = blockIdx.y;
  const int b = bh >> 3, h = bh & 7;
  for (int t = tid; t < 257; t += 512) blds[t] = bias[t * H + h];
  const int qb0 = qt * 256;
  bf16x8 qf0[2], qf1[2];
  int qr[2][4];
#pragma unroll
  for (int g = 0; g < 2; ++g) {
    const size_t qoff =
        (size_t)(b * S + qb0 + w * 32 + g * 16 + lr) * ldqk + h * 64;
    qf0[g] = *(const bf16x8*)(qkv + qoff + lg * 8);
    qf1[g] = *(const bf16x8*)(qkv + qoff + 32 + lg * 8);
#pragma unroll
    for (int i = 0; i < 4; ++i) qr[g][i] = qb0 + w * 32 + g * 16 + lg * 4 + i;
  }

  f32x4 acc[2][16] = {};
  float m0[2][4], l0[2][4];
#pragma unroll
  for (int g = 0; g < 2; ++g)
#pragma unroll
    for (int i = 0; i < 4; ++i) { m0[g][i] = -__builtin_inff(); l0[g][i] = 0.f; }

  const int sr = tid >> 3, sj = tid & 7;
  const int ksw = (sj ^ (sr & 7)) << 3;
  const bf16_t* kbase = qkv + 512 + (size_t)(b * S + sr) * ldqk + h * 64 + ksw;
  const bf16_t* vbase = vt + (size_t)((b * H + h) * 256 + sr) * 1024 + ksw;

  auto STAGE = [&](int kt, int bs) {
    GLL16(kbase + (size_t)(kt * 64) * ldqk, &Klds[bs][w * 512]);
#pragma unroll
    for (int qq = 0; qq < 4; ++qq)
      GLL16(vbase + (size_t)(qq * 64) * 1024 + kt * 64,
            &Vlds[bs][qq * 4096 + w * 512]);
  };

  STAGE(0, 0);
  STAGE(1, 1);

  for (int kt = 0; kt <= 15; ++kt) {
    const int buf = kt % 3;
    if (kt < 15) {
      asm volatile("s_waitcnt vmcnt(5)" ::: "memory");
    } else {
      asm volatile("s_waitcnt vmcnt(0)" ::: "memory");
    }
    __builtin_amdgcn_s_barrier();
    if (kt + 2 <= 15) STAGE(kt + 2, (kt + 2) % 3);

    const int kvlo = kt * 64;
    f32x4 sf[2][4];
    __builtin_amdgcn_s_setprio(1);
#pragma unroll
    for (int n = 0; n < 4; ++n) {
      const int R = n * 16 + lr, rs = lr & 7;
      bf16x8 kb0 = *(const bf16x8*)&Klds[buf][R * 64 + ((lg ^ rs) << 3)];
      bf16x8 kb1 = *(const bf16x8*)&Klds[buf][R * 64 + (((4 + lg) ^ rs) << 3)];
#pragma unroll
      for (int g = 0; g < 2; ++g) {
        f32x4 z = {0.f, 0.f, 0.f, 0.f};
        z = mfma16(qf0[g], kb0, z);
        z = mfma16(qf1[g], kb1, z);
        sf[g][n] = z;
      }
    }
    __builtin_amdgcn_s_setprio(0);
    bool sat = false;
    float cb = 0.f;
    if (kvlo + 63 <= qb0 - 128) { sat = true; cb = blds[0]; }
    else if (kvlo >= qb0 + 384) { sat = true; cb = blds[256]; }
    float tmL[2][4];
#pragma unroll
    for (int g = 0; g < 2; ++g)
#pragma unroll
      for (int i = 0; i < 4; ++i) tmL[g][i] = -__builtin_inff();
    if (sat) {
#pragma unroll
      for (int g = 0; g < 2; ++g)
#pragma unroll
        for (int n = 0; n < 4; ++n)
#pragma unroll
          for (int i = 0; i < 4; ++i) {
            float val = sf[g][n][i] * 0.125f + cb;
            sf[g][n][i] = val;
            tmL[g][i] = fmaxf(tmL[g][i], val);
          }
    } else {
#pragma unroll
      for (int n = 0; n < 4; ++n) {
        int kv = kvlo + n * 16 + lr;
#pragma unroll
        for (int g = 0; g < 2; ++g)
#pragma unroll
          for (int i = 0; i < 4; ++i) {
            int rel = kv - qr[g][i];
            int idx = imin(imax(rel, -128), 128) + 128;
            float val = sf[g][n][i] * 0.125f + blds[idx];
            sf[g][n][i] = val;
            tmL[g][i] = fmaxf(tmL[g][i], val);
          }
      }
    }
#pragma unroll
    for (int g = 0; g < 2; ++g) {
      bool need = false;
#pragma unroll
      for (int i = 0; i < 4; ++i) need |= (tmL[g][i] > m0[g][i] + 8.0f);
      if (__any(need ? 1 : 0)) {
        float corr[4];
#pragma unroll
        for (int i = 0; i < 4; ++i) {
          float tm = tmL[g][i];
#pragma unroll
          for (int off = 1; off < 16; off <<= 1)
            tm = fmaxf(tm, __shfl_xor(tm, off));
          float nm = fmaxf(m0[g][i], tm);
          corr[i] = __expf(m0[g][i] - nm);
          m0[g][i] = nm;
          l0[g][i] *= corr[i];
        }
        f32x4 cv = {corr[0], corr[1], corr[2], corr[3]};
#pragma unroll
        for (int nf = 0; nf < 16; ++nf) acc[g][nf] *= cv;
      }
#pragma unroll
      for (int n = 0; n < 4; ++n)
#pragma unroll
        for (int i = 0; i < 4; ++i) {
          float p = __expf(sf[g][n][i] - m0[g][i]);
          sf[g][n][i] = p;
          l0[g][i] += p;
        }
#pragma unroll
      for (int n = 0; n < 4; ++n)
#pragma unroll
        for (int i = 0; i < 4; ++i) {
          int r = lg * 4 + i, cb2 = n * 16 + lr;
          Plds[w][g][r * 64 + (((cb2 >> 3) ^ (r & 7)) << 3) + (cb2 & 7)] =
              (bf16_t)sf[g][n][i];
        }
    }
    __builtin_amdgcn_s_setprio(1);
#pragma unroll
    for (int c = 0; c < 2; ++c) {
      bf16x8 pa[2];
#pragma unroll
      for (int g = 0; g < 2; ++g)
        pa[g] = *(const bf16x8*)&Plds[w][g][lr * 64 +
                                            (((c * 4 + lg) ^ (lr & 7)) << 3)];
#pragma unroll
      for (int nf = 0; nf < 16; ++nf) {
        const int R = nf * 16 + lr;
        bf16x8 vb = *(const bf16x8*)&Vlds[buf][R * 64 +
                                               (((c * 4 + lg) ^ (lr & 7)) << 3)];
        acc[0][nf] = mfma16(pa[0], vb, acc[0][nf]);
        acc[1][nf] = mfma16(pa[1], vb, acc[1][nf]);
      }
    }
    __builtin_amdgcn_s_setprio(0);
  }
#pragma unroll
  for (int g = 0; g < 2; ++g) {
    float rcp[4];
#pragma unroll
    for (int i = 0; i < 4; ++i) {
      float l = l0[g][i];
#pragma unroll
      for (int off = 1; off < 16; off <<= 1) l += __shfl_xor(l, off);
      rcp[i] = 1.f / l;
    }
#pragma unroll
    for (int nf = 0; nf < 16; ++nf)
#pragma unroll
      for (int i = 0; i < 4; ++i)
        o[(size_t)(b * S + qr[g][i]) * ldo + h * 256 + nf * 16 + lr] =
            (bf16_t)(acc[g][nf][i] * rcp[i]);
  }
}

// ---------------------------------------------------------------------------
extern "C" void kernel_launch(void* const* d_in, const int* in_sizes, int n_in,
                              void* d_out, int out_size, void* d_ws,
                              size_t ws_size, hipStream_t stream) {
  const int* xs = (const int*)d_in[0];
  const float* emb = (const float*)d_in[1];
  const float* Wq_l = (const float*)d_in[2];
  const float* Wk_l = (const float*)d_in[3];
  const float* Wv_l = (const float*)d_in[4];
  const float* Wo_l = (const float*)d_in[5];
  const float* bias_l = (const float*)d_in[6];
  const float* Wq_g = (const float*)d_in[7];
  const float* Wk_g = (const float*)d_in[8];
  const float* Wv_g = (const float*)d_in[9];
  const float* Wo_g = (const float*)d_in[10];
  const float* bias_g = (const float*)d_in[11];
  const float* Wq_p = (const float*)d_in[12];
  const float* Wk_p = (const float*)d_in[13];
  const float* Wv_p = (const float*)d_in[14];
  const float* Wo_p = (const float*)d_in[15];
  const float* bias_p = (const float*)d_in[16];
  const float* W_out = (const float*)d_in[17];
  const float* b_out = (const float*)d_in[18];

  char* ws = (char*)d_ws;
  size_t off = 0;
  auto alloc = [&](size_t bytes) -> char* {
    char* p = ws + off;
    off = (off + bytes + 255) & ~(size_t)255;
    return p;
  };
  bf16_t* wqkv_l = (bf16_t*)alloc((size_t)3072 * 256 * 2);
  bf16_t* wqkv_g = (bf16_t*)alloc((size_t)3072 * 256 * 2);
  bf16_t* wqkv_p = (bf16_t*)alloc((size_t)3072 * 512 * 2);
  bf16_t* wo_l_t = (bf16_t*)alloc((size_t)256 * 2048 * 2);
  bf16_t* wo_g_t = (bf16_t*)alloc((size_t)256 * 2048 * 2);
  bf16_t* wo_p_t = (bf16_t*)alloc((size_t)256 * 2048 * 2);
  bf16_t* w_out_t = (bf16_t*)alloc((size_t)240 * 256 * 2);
  bf16_t* xb = (bf16_t*)alloc((size_t)8192 * 256 * 2);
  bf16_t* qkv = (bf16_t*)alloc((size_t)8192 * 3072 * 2);
  bf16_t* vtb = (bf16_t*)alloc((size_t)8192 * 2048 * 2);
  bf16_t* h2 = (bf16_t*)alloc((size_t)8192 * 512 * 2);
  bf16_t* h3 = (bf16_t*)alloc((size_t)8192 * 256 * 2);

  if (off > ws_size) {
    sentinel_k<<<1, 1, 0, stream>>>((float*)d_out);
    return;
  }

  WPack wp;
  wp.e[0] = {Wq_l, wqkv_l, 256, 512};
  wp.e[1] = {Wk_l, wqkv_l + 512 * 256, 256, 512};
  wp.e[2] = {Wv_l, wqkv_l + 1024 * 256, 256, 2048};
  wp.e[3] = {Wq_g, wqkv_g, 256, 512};
  wp.e[4] = {Wk_g, wqkv_g + 512 * 256, 256, 512};
  wp.e[5] = {Wv_g, wqkv_g + 1024 * 256, 256, 2048};
  wp.e[6] = {Wq_p, wqkv_p, 512, 512};
  wp.e[7] = {Wk_p, wqkv_p + 512 * 512, 512, 512};
  wp.e[8] = {Wv_p, wqkv_p + 1024 * 512, 512, 2048};
  wp.e[9] = {Wo_l, wo_l_t, 2048, 256};
  wp.e[10] = {Wo_g, wo_g_t, 2048, 256};
  wp.e[11] = {Wo_p, wo_p_t, 2048, 256};
  wp.e[12] = {W_out, w_out_t, 256, 240};
  wcast_all<<<dim3(512, 13), 256, 0, stream>>>(wp);

  embed_k<<<8192, 256, 0, stream>>>(xs, emb, xb);

  auto gemm_small = [&](const bf16_t* A, int lda, const bf16_t* Bt, int K,
                        int N, void* C, int ldc, const float* bias) {
    dim3 g((N + 127) / 128, 256);
    if (bias)
      gemm_btm<32, true><<<g, 256, 0, stream>>>(A, lda, Bt, K, C, ldc, bias, N);
    else
      gemm_btm<32, false><<<g, 256, 0, stream>>>(A, lda, Bt, K, C, ldc, nullptr, N);
  };

  dim3 qg(24, 64), ag(64, 8), ag4(64, 4);
  // ---- local layer ----
  gemm_bt<false, true><<<qg, 256, 0, stream>>>(xb, 256, wqkv_l, 256, qkv, 3072,
                                               nullptr, 3072, vtb);
  attn_k<0><<<ag, 512, 0, stream>>>(qkv, vtb, bias_l, qkv + 1024, 3072, 3072);
  gemm_small(qkv + 1024, 3072, wo_l_t, 2048, 256, h2, 512, nullptr);
  // ---- global layer (QBLK=256) ----
  gemm_bt<false, true><<<qg, 256, 0, stream>>>(xb, 256, wqkv_g, 256, qkv, 3072,
                                               nullptr, 3072, vtb);
  attn_g256<<<ag4, 512, 0, stream>>>(qkv, vtb, bias_g, qkv + 1024, 3072, 3072);
  gemm_small(qkv + 1024, 3072, wo_g_t, 2048, 256, h2 + 256, 512, nullptr);
  // ---- predictive (causal) layer on h2 [8192,512] ----
  gemm_bt<false, true><<<qg, 256, 0, stream>>>(h2, 512, wqkv_p, 512, qkv, 3072,
                                               nullptr, 3072, vtb);
  attn_k<2><<<ag, 512, 0, stream>>>(qkv, vtb, bias_p, qkv + 1024, 3072, 3072);
  gemm_small(qkv + 1024, 3072, wo_p_t, 2048, 256, h3, 256, nullptr);
  // ---- head ----
  gemm_small(h3, 256, w_out_t, 256, 240, (float*)d_out, 240, b_out);
}

// Round 16
// 375.968 us; speedup vs baseline: 1.0311x; 1.0311x over previous
//
#include <hip/hip_runtime.h>
#include <hip/hip_bf16.h>

// ---------------------------------------------------------------------------
// Model: B=8 S=1024 D=256 H=8 DK=64 DV=256; LB=LF=32, CUT=128, VOCAB=240
// R14 config (best: 375.7us): 2-phase dbuf GEMMs (TLP-hidden) + 3-deep
// counted-vmcnt attn (ILP-hidden, 1 block/CU). Prep launches fused.
// ---------------------------------------------------------------------------

typedef __bf16 bf16_t;
typedef __bf16 bf16x4 __attribute__((ext_vector_type(4)));
typedef __bf16 bf16x8 __attribute__((ext_vector_type(8)));
typedef float f32x4 __attribute__((ext_vector_type(4)));

__device__ __forceinline__ f32x4 mfma16(bf16x8 a, bf16x8 b, f32x4 c) {
  return __builtin_amdgcn_mfma_f32_16x16x32_bf16(a, b, c, 0, 0, 0);
}

#define GLL16(GP, LP)                                                          \
  __builtin_amdgcn_global_load_lds(                                            \
      (const __attribute__((address_space(1))) void*)(GP),                     \
      (__attribute__((address_space(3))) void*)(LP), 16, 0, 0)

__device__ __forceinline__ int imin(int a, int b) { return a < b ? a : b; }
__device__ __forceinline__ int imax(int a, int b) { return a > b ? a : b; }

// ---- weight transposes+casts AND embedding gather in one launch ------------
struct WEnt { const float* src; bf16_t* dst; int K; int N; };
struct WPack { WEnt e[13]; };

__global__ void prep_all(WPack p, const int* __restrict__ xs,
                         const float* __restrict__ emb,
                         bf16_t* __restrict__ xb) {
  if (blockIdx.y == 13) {  // embedding gather
    for (int id = blockIdx.x * 256 + threadIdx.x; id < 8192 * 256;
         id += gridDim.x * 256) {
      int row = id >> 8, d = id & 255;
      xb[id] = (bf16_t)emb[(size_t)xs[row] * 256 + d];
    }
    return;
  }
  const WEnt E = p.e[blockIdx.y];
  const int tot = E.K * E.N;
  for (int id = blockIdx.x * 256 + threadIdx.x; id < tot; id += gridDim.x * 256) {
    int n = id / E.K, k = id - n * E.K;
    E.dst[id] = (bf16_t)E.src[(size_t)k * E.N + n];
  }
}

__global__ void sentinel_k(float* out) { out[0] = 1.0e6f; }

// ---- GEMM 128x128, 2-phase dbuf: C = A[M,K] * Bt[N,K]^T --------------------
template <bool F32OUT, bool VT>
__global__ __launch_bounds__(256) void gemm_bt(
    const bf16_t* __restrict__ A, int lda, const bf16_t* __restrict__ Bt, int K,
    void* __restrict__ Cv, int ldc, const float* __restrict__ bias, int N,
    bf16_t* __restrict__ vt) {
  __shared__ bf16_t As[2][128 * 32];
  __shared__ bf16_t Bs[2][128 * 32];
  const int tid = threadIdx.x;
  const int lane = tid & 63, wave = tid >> 6;
  const int wr = wave >> 1, wc = wave & 1;
  const int lr = lane & 15, lg = lane >> 4;
  const int bm = blockIdx.y, bn = blockIdx.x;

  const int ar = tid >> 2;
  const int ac = (tid & 3) * 8;
  const bf16_t* a0 = A + (size_t)(bm * 128 + ar) * lda + ac;
  const bf16_t* a1 = A + (size_t)(bm * 128 + 64 + ar) * lda + ac;
  int br0 = imin(bn * 128 + ar, N - 1);
  int br1 = imin(bn * 128 + 64 + ar, N - 1);
  const bf16_t* b0 = Bt + (size_t)br0 * K + ac;
  const bf16_t* b1 = Bt + (size_t)br1 * K + ac;

  f32x4 acc[4][4] = {};
  const int nk = K >> 5;

  auto STAGE = [&](int kt, int bs) {
    const int ko = kt * 32;
    GLL16(a0 + ko, &As[bs][wave * 512]);
    GLL16(a1 + ko, &As[bs][2048 + wave * 512]);
    GLL16(b0 + ko, &Bs[bs][wave * 512]);
    GLL16(b1 + ko, &Bs[bs][2048 + wave * 512]);
  };

  STAGE(0, 0);
  asm volatile("s_waitcnt vmcnt(0)" ::: "memory");
  __syncthreads();
  int cur = 0;
  for (int kt = 0; kt < nk; ++kt) {
    const bool pf = (kt + 1 < nk);
    if (pf) STAGE(kt + 1, cur ^ 1);
    bf16x8 af[4], bfv[4];
#pragma unroll
    for (int m = 0; m < 4; ++m)
      af[m] = *(const bf16x8*)&As[cur][(wr * 64 + m * 16 + lr) * 32 + lg * 8];
#pragma unroll
    for (int n = 0; n < 4; ++n)
      bfv[n] = *(const bf16x8*)&Bs[cur][(wc * 64 + n * 16 + lr) * 32 + lg * 8];
    __builtin_amdgcn_s_setprio(1);
#pragma unroll
    for (int m = 0; m < 4; ++m)
#pragma unroll
      for (int n = 0; n < 4; ++n) acc[m][n] = mfma16(af[m], bfv[n], acc[m][n]);
    __builtin_amdgcn_s_setprio(0);
    if (pf) {
      asm volatile("s_waitcnt vmcnt(0)" ::: "memory");
      __syncthreads();
      cur ^= 1;
    }
  }
  const int r0 = bm * 128 + wr * 64;
  const int c0 = bn * 128 + wc * 64;
  if (VT && c0 >= 1024) {
    const int bq = r0 >> 10;
    const int s0 = r0 & 1023;
#pragma unroll
    for (int m = 0; m < 4; ++m)
#pragma unroll
      for (int n = 0; n < 4; ++n) {
        int c = c0 + n * 16 + lr;
        bf16x4 pk;
#pragma unroll
        for (int i = 0; i < 4; ++i) pk[i] = (bf16_t)acc[m][n][i];
        *(bf16x4*)(vt + (size_t)(bq * 2048 + (c - 1024)) * 1024 + s0 + m * 16 +
                   lg * 4) = pk;
      }
  } else {
#pragma unroll
    for (int m = 0; m < 4; ++m)
#pragma unroll
      for (int n = 0; n < 4; ++n) {
        int c = c0 + n * 16 + lr;
        if (c >= N) continue;
#pragma unroll
        for (int i = 0; i < 4; ++i) {
          int r = r0 + m * 16 + lg * 4 + i;
          if (F32OUT)
            ((float*)Cv)[(size_t)r * ldc + c] = acc[m][n][i] + bias[c];
          else
            ((bf16_t*)Cv)[(size_t)r * ldc + c] = (bf16_t)acc[m][n][i];
        }
      }
  }
}

// ---- GEMM BMx128, 2-phase dbuf, swapped operands (vectorized epilogue) -----
template <int BM, bool F32OUT>
__global__ __launch_bounds__(256) void gemm_btm(
    const bf16_t* __restrict__ A, int lda, const bf16_t* __restrict__ Bt, int K,
    void* __restrict__ Cv, int ldc, const float* __restrict__ bias, int N) {
  constexpr int MF = BM / 32;
  __shared__ bf16_t As[2][BM * 32];
  __shared__ bf16_t Bs[2][128 * 32];
  const int tid = threadIdx.x;
  const int lane = tid & 63, wave = tid >> 6;
  const int wr = wave >> 1, wc = wave & 1;
  const int lr = lane & 15, lg = lane >> 4;
  const int bm = blockIdx.y, bn = blockIdx.x;

  const int ar = tid >> 2;
  const int ac = (tid & 3) * 8;
  const bf16_t* a0 = A + (size_t)(bm * BM + (BM == 32 ? (ar & 31) : ar)) * lda + ac;
  int br0 = imin(bn * 128 + ar, N - 1);
  int br1 = imin(bn * 128 + 64 + ar, N - 1);
  const bf16_t* b0 = Bt + (size_t)br0 * K + ac;
  const bf16_t* b1 = Bt + (size_t)br1 * K + ac;

  f32x4 acc[MF][4] = {};
  const int nk = K >> 5;

  auto STAGE = [&](int kt, int bs) {
    const int ko = kt * 32;
    if (BM == 64) {
      GLL16(a0 + ko, &As[bs][wave * 512]);
    } else {
      if (wave < 2) GLL16(a0 + ko, &As[bs][wave * 512]);
    }
    GLL16(b0 + ko, &Bs[bs][wave * 512]);
    GLL16(b1 + ko, &Bs[bs][2048 + wave * 512]);
  };

  STAGE(0, 0);
  asm volatile("s_waitcnt vmcnt(0)" ::: "memory");
  __syncthreads();
  int cur = 0;
  for (int kt = 0; kt < nk; ++kt) {
    const bool pf = (kt + 1 < nk);
    if (pf) STAGE(kt + 1, cur ^ 1);
    bf16x8 af[MF], bfv[4];
#pragma unroll
    for (int m = 0; m < MF; ++m)
      af[m] = *(const bf16x8*)&As[cur][(wr * (BM / 2) + m * 16 + lr) * 32 + lg * 8];
#pragma unroll
    for (int n = 0; n < 4; ++n)
      bfv[n] = *(const bf16x8*)&Bs[cur][(wc * 64 + n * 16 + lr) * 32 + lg * 8];
    __builtin_amdgcn_s_setprio(1);
#pragma unroll
    for (int m = 0; m < MF; ++m)
#pragma unroll
      for (int n = 0; n < 4; ++n) acc[m][n] = mfma16(bfv[n], af[m], acc[m][n]);
    __builtin_amdgcn_s_setprio(0);
    if (pf) {
      asm volatile("s_waitcnt vmcnt(0)" ::: "memory");
      __syncthreads();
      cur ^= 1;
    }
  }
  const int r0 = bm * BM + wr * (BM / 2);
  const int c0 = bn * 128 + wc * 64;
#pragma unroll
  for (int m = 0; m < MF; ++m) {
    const int r = r0 + m * 16 + lr;
#pragma unroll
    for (int n = 0; n < 4; ++n) {
      const int c = c0 + n * 16 + lg * 4;
      if (c >= N) continue;
      if (F32OUT) {
        float4 bv = *(const float4*)&bias[c];
        float4 ov = {acc[m][n][0] + bv.x, acc[m][n][1] + bv.y,
                     acc[m][n][2] + bv.z, acc[m][n][3] + bv.w};
        *(float4*)&((float*)Cv)[(size_t)r * ldc + c] = ov;
      } else {
        bf16x4 pk;
#pragma unroll
        for (int i = 0; i < 4; ++i) pk[i] = (bf16_t)acc[m][n][i];
        *(bf16x4*)&((bf16_t*)Cv)[(size_t)r * ldc + c] = pk;
      }
    }
  }
}

// ---- fused flash attention QBLK=128 — LOCAL / CAUSAL (3-deep pipeline) -----
// Counted vmcnt(5) mid-loop + raw s_barrier (never vmcnt(0) mid-loop).
template <int VAR>
__global__ __launch_bounds__(512) void attn_k(
    const bf16_t* __restrict__ qkv, const bf16_t* __restrict__ vt,
    const float* __restrict__ bias, bf16_t* __restrict__ o, int ldqk, int ldo) {
  constexpr int S = 1024, H = 8;
  __shared__ bf16_t Klds[3][64 * 64];
  __shared__ bf16_t Vlds[3][256 * 64];
  __shared__ bf16_t Plds[8][16 * 64];
  __shared__ float blds[260];
  const int tid = threadIdx.x, lane = tid & 63, w = tid >> 6;
  const int lr = lane & 15, lg = lane >> 4;
  const int bh = blockIdx.x;
  const int qt = (VAR == 2) ? (7 - (int)blockIdx.y) : blockIdx.y;  // LPT
  const int b = bh >> 3, h = bh & 7;
  const int TSIZE = (VAR == 0) ? 65 : 257;
  for (int t = tid; t < TSIZE; t += 512) blds[t] = bias[t * H + h];
  const int qb0 = qt * 128;
#define QROW(j) (VAR == 2 ? qb0 + (j) * 8 + w : qb0 + w * 16 + (j))
  const size_t qoff = (size_t)(b * S + QROW(lr)) * ldqk + h * 64;
  bf16x8 qf0 = *(const bf16x8*)(qkv + qoff + lg * 8);
  bf16x8 qf1 = *(const bf16x8*)(qkv + qoff + 32 + lg * 8);
  int qr[4];
#pragma unroll
  for (int i = 0; i < 4; ++i) qr[i] = QROW(lg * 4 + i);

  f32x4 acc[16] = {};
  float m0[4], l0[4];
#pragma unroll
  for (int i = 0; i < 4; ++i) { m0[i] = -__builtin_inff(); l0[i] = 0.f; }
  int kt0 = 0, kt1 = 15;
  if (VAR == 0) {
    kt0 = imax(0, (qb0 - 32) >> 6);
    kt1 = imin(15, (qb0 + 127 + 32) >> 6);
  }
  if (VAR == 2) kt1 = 2 * qt + 1;

  const int sr = tid >> 3, sj = tid & 7;
  const int ksw = (sj ^ (sr & 7)) << 3;
  const bf16_t* kbase = qkv + 512 + (size_t)(b * S + sr) * ldqk + h * 64 + ksw;
  const bf16_t* vbase = vt + (size_t)((b * H + h) * 256 + sr) * 1024 + ksw;
  bf16_t* Pw = &Plds[w][0];

  auto STAGE = [&](int kt, int bs) {
    GLL16(kbase + (size_t)(kt * 64) * ldqk, &Klds[bs][w * 512]);
#pragma unroll
    for (int qq = 0; qq < 4; ++qq)
      GLL16(vbase + (size_t)(qq * 64) * 1024 + kt * 64,
            &Vlds[bs][qq * 4096 + w * 512]);
  };

  STAGE(kt0, 0);
  if (kt0 + 1 <= kt1) STAGE(kt0 + 1, 1);

  for (int kt = kt0; kt <= kt1; ++kt) {
    const int buf = (kt - kt0) % 3;
    if (kt < kt1) {
      asm volatile("s_waitcnt vmcnt(5)" ::: "memory");
    } else {
      asm volatile("s_waitcnt vmcnt(0)" ::: "memory");
    }
    __builtin_amdgcn_s_barrier();
    if (kt + 2 <= kt1) STAGE(kt + 2, (kt + 2 - kt0) % 3);

    const int kvlo = kt * 64;
    bool active = true;
    if (VAR == 0) {
      int q0w = qb0 + w * 16;
      active = (kvlo + 63 >= q0w - 32) && (kvlo <= q0w + 47);
    }
    if (VAR == 2) active = (kvlo <= qb0 + 120 + w);
    if (active) {
      f32x4 sf[4];
      __builtin_amdgcn_s_setprio(1);
#pragma unroll
      for (int n = 0; n < 4; ++n) {
        const int R = n * 16 + lr, rs = lr & 7;
        bf16x8 kb0 = *(const bf16x8*)&Klds[buf][R * 64 + ((lg ^ rs) << 3)];
        bf16x8 kb1 = *(const bf16x8*)&Klds[buf][R * 64 + (((4 + lg) ^ rs) << 3)];
        f32x4 z = {0.f, 0.f, 0.f, 0.f};
        z = mfma16(qf0, kb0, z);
        z = mfma16(qf1, kb1, z);
        sf[n] = z;
      }
      __builtin_amdgcn_s_setprio(0);
      bool sat = false;
      float cb = 0.f;
      if (VAR == 2) {
        if (kvlo + 63 <= qb0 - 128) { sat = true; cb = blds[0]; }
      }
      float tmL[4];
#pragma unroll
      for (int i = 0; i < 4; ++i) tmL[i] = -__builtin_inff();
      if (sat) {
#pragma unroll
        for (int n = 0; n < 4; ++n)
#pragma unroll
          for (int i = 0; i < 4; ++i) {
            float val = sf[n][i] * 0.125f + cb;
            sf[n][i] = val;
            tmL[i] = fmaxf(tmL[i], val);
          }
      } else {
#pragma unroll
        for (int n = 0; n < 4; ++n) {
          int kv = kvlo + n * 16 + lr;
#pragma unroll
          for (int i = 0; i < 4; ++i) {
            int rel = kv - qr[i];
            float val;
            if (VAR == 0) {
              val = (rel >= -32 && rel <= 32)
                        ? sf[n][i] * 0.125f + blds[rel + 32] : -1e9f;
            } else {
              int idx = imax(rel, -128) + 128;
              val = (rel <= 0) ? sf[n][i] * 0.125f + blds[idx] : -1e9f;
            }
            sf[n][i] = val;
            tmL[i] = fmaxf(tmL[i], val);
          }
        }
      }
      bool need = false;
#pragma unroll
      for (int i = 0; i < 4; ++i) need |= (tmL[i] > m0[i] + 8.0f);
      if (__any(need ? 1 : 0)) {
        float corr[4];
#pragma unroll
        for (int i = 0; i < 4; ++i) {
          float tm = tmL[i];
#pragma unroll
          for (int off = 1; off < 16; off <<= 1)
            tm = fmaxf(tm, __shfl_xor(tm, off));
          float nm = fmaxf(m0[i], tm);
          corr[i] = __expf(m0[i] - nm);
          m0[i] = nm;
          l0[i] *= corr[i];
        }
        f32x4 cv = {corr[0], corr[1], corr[2], corr[3]};
#pragma unroll
        for (int nf = 0; nf < 16; ++nf) acc[nf] *= cv;
      }
#pragma unroll
      for (int n = 0; n < 4; ++n)
#pragma unroll
        for (int i = 0; i < 4; ++i) {
          float p = __expf(sf[n][i] - m0[i]);
          sf[n][i] = p;
          l0[i] += p;
        }
#pragma unroll
      for (int n = 0; n < 4; ++n)
#pragma unroll
        for (int i = 0; i < 4; ++i) {
          int r = lg * 4 + i, cb2 = n * 16 + lr;
          Pw[r * 64 + (((cb2 >> 3) ^ (r & 7)) << 3) + (cb2 & 7)] =
              (bf16_t)sf[n][i];
        }
      __builtin_amdgcn_s_setprio(1);
#pragma unroll
      for (int c = 0; c < 2; ++c) {
        bf16x8 pa = *(const bf16x8*)&Pw[lr * 64 + (((c * 4 + lg) ^ (lr & 7)) << 3)];
#pragma unroll
        for (int nf = 0; nf < 16; ++nf) {
          const int R = nf * 16 + lr;
          bf16x8 vb = *(const bf16x8*)&Vlds[buf][R * 64 + (((c * 4 + lg) ^ (lr & 7)) << 3)];
          acc[nf] = mfma16(pa, vb, acc[nf]);
        }
      }
      __builtin_amdgcn_s_setprio(0);
    }
  }
  float rcp[4];
#pragma unroll
  for (int i = 0; i < 4; ++i) {
    float l = l0[i];
#pragma unroll
    for (int off = 1; off < 16; off <<= 1) l += __shfl_xor(l, off);
    rcp[i] = 1.f / l;
  }
#pragma unroll
  for (int nf = 0; nf < 16; ++nf)
#pragma unroll
    for (int i = 0; i < 4; ++i)
      o[(size_t)(b * S + qr[i]) * ldo + h * 256 + nf * 16 + lr] =
          (bf16_t)(acc[nf][i] * rcp[i]);
#undef QROW
}

// ---- fused flash attention QBLK=256 — GLOBAL (3-deep pipeline) -------------
__global__ __launch_bounds__(512) void attn_g256(
    const bf16_t* __restrict__ qkv, const bf16_t* __restrict__ vt,
    const float* __restrict__ bias, bf16_t* __restrict__ o, int ldqk, int ldo) {
  constexpr int S = 1024, H = 8;
  __shared__ bf16_t Klds[3][64 * 64];
  __shared__ bf16_t Vlds[3][256 * 64];
  __shared__ bf16_t Plds[8][2][16 * 64];
  __shared__ float blds[260];
  const int tid = threadIdx.x, lane = tid & 63, w = tid >> 6;
  const int lr = lane & 15, lg = lane >> 4;
  const int bh = blockIdx.x, qt = blockIdx.y;
  const int b = bh >> 3, h = bh & 7;
  for (int t = tid; t < 257; t += 512) blds[t] = bias[t * H + h];
  const int qb0 = qt * 256;
  bf16x8 qf0[2], qf1[2];
  int qr[2][4];
#pragma unroll
  for (int g = 0; g < 2; ++g) {
    const size_t qoff =
        (size_t)(b * S + qb0 + w * 32 + g * 16 + lr) * ldqk + h * 64;
    qf0[g] = *(const bf16x8*)(qkv + qoff + lg * 8);
    qf1[g] = *(const bf16x8*)(qkv + qoff + 32 + lg * 8);
#pragma unroll
    for (int i = 0; i < 4; ++i) qr[g][i] = qb0 + w * 32 + g * 16 + lg * 4 + i;
  }

  f32x4 acc[2][16] = {};
  float m0[2][4], l0[2][4];
#pragma unroll
  for (int g = 0; g < 2; ++g)
#pragma unroll
    for (int i = 0; i < 4; ++i) { m0[g][i] = -__builtin_inff(); l0[g][i] = 0.f; }

  const int sr = tid >> 3, sj = tid & 7;
  const int ksw = (sj ^ (sr & 7)) << 3;
  const bf16_t* kbase = qkv + 512 + (size_t)(b * S + sr) * ldqk + h * 64 + ksw;
  const bf16_t* vbase = vt + (size_t)((b * H + h) * 256 + sr) * 1024 + ksw;

  auto STAGE = [&](int kt, int bs) {
    GLL16(kbase + (size_t)(kt * 64) * ldqk, &Klds[bs][w * 512]);
#pragma unroll
    for (int qq = 0; qq < 4; ++qq)
      GLL16(vbase + (size_t)(qq * 64) * 1024 + kt * 64,
            &Vlds[bs][qq * 4096 + w * 512]);
  };

  STAGE(0, 0);
  STAGE(1, 1);

  for (int kt = 0; kt <= 15; ++kt) {
    const int buf = kt % 3;
    if (kt < 15) {
      asm volatile("s_waitcnt vmcnt(5)" ::: "memory");
    } else {
      asm volatile("s_waitcnt vmcnt(0)" ::: "memory");
    }
    __builtin_amdgcn_s_barrier();
    if (kt + 2 <= 15) STAGE(kt + 2, (kt + 2) % 3);

    const int kvlo = kt * 64;
    f32x4 sf[2][4];
    __builtin_amdgcn_s_setprio(1);
#pragma unroll
    for (int n = 0; n < 4; ++n) {
      const int R = n * 16 + lr, rs = lr & 7;
      bf16x8 kb0 = *(const bf16x8*)&Klds[buf][R * 64 + ((lg ^ rs) << 3)];
      bf16x8 kb1 = *(const bf16x8*)&Klds[buf][R * 64 + (((4 + lg) ^ rs) << 3)];
#pragma unroll
      for (int g = 0; g < 2; ++g) {
        f32x4 z = {0.f, 0.f, 0.f, 0.f};
        z = mfma16(qf0[g], kb0, z);
        z = mfma16(qf1[g], kb1, z);
        sf[g][n] = z;
      }
    }
    __builtin_amdgcn_s_setprio(0);
    bool sat = false;
    float cb = 0.f;
    if (kvlo + 63 <= qb0 - 128) { sat = true; cb = blds[0]; }
    else if (kvlo >= qb0 + 384) { sat = true; cb = blds[256]; }
    float tmL[2][4];
#pragma unroll
    for (int g = 0; g < 2; ++g)
#pragma unroll
      for (int i = 0; i < 4; ++i) tmL[g][i] = -__builtin_inff();
    if (sat) {
#pragma unroll
      for (int g = 0; g < 2; ++g)
#pragma unroll
        for (int n = 0; n < 4; ++n)
#pragma unroll
          for (int i = 0; i < 4; ++i) {
            float val = sf[g][n][i] * 0.125f + cb;
            sf[g][n][i] = val;
            tmL[g][i] = fmaxf(tmL[g][i], val);
          }
    } else {
#pragma unroll
      for (int n = 0; n < 4; ++n) {
        int kv = kvlo + n * 16 + lr;
#pragma unroll
        for (int g = 0; g < 2; ++g)
#pragma unroll
          for (int i = 0; i < 4; ++i) {
            int rel = kv - qr[g][i];
            int idx = imin(imax(rel, -128), 128) + 128;
            float val = sf[g][n][i] * 0.125f + blds[idx];
            sf[g][n][i] = val;
            tmL[g][i] = fmaxf(tmL[g][i], val);
          }
      }
    }
#pragma unroll
    for (int g = 0; g < 2; ++g) {
      bool need = false;
#pragma unroll
      for (int i = 0; i < 4; ++i) need |= (tmL[g][i] > m0[g][i] + 8.0f);
      if (__any(need ? 1 : 0)) {
        float corr[4];
#pragma unroll
        for (int i = 0; i < 4; ++i) {
          float tm = tmL[g][i];
#pragma unroll
          for (int off = 1; off < 16; off <<= 1)
            tm = fmaxf(tm, __shfl_xor(tm, off));
          float nm = fmaxf(m0[g][i], tm);
          corr[i] = __expf(m0[g][i] - nm);
          m0[g][i] = nm;
          l0[g][i] *= corr[i];
        }
        f32x4 cv = {corr[0], corr[1], corr[2], corr[3]};
#pragma unroll
        for (int nf = 0; nf < 16; ++nf) acc[g][nf] *= cv;
      }
#pragma unroll
      for (int n = 0; n < 4; ++n)
#pragma unroll
        for (int i = 0; i < 4; ++i) {
          float p = __expf(sf[g][n][i] - m0[g][i]);
          sf[g][n][i] = p;
          l0[g][i] += p;
        }
#pragma unroll
      for (int n = 0; n < 4; ++n)
#pragma unroll
        for (int i = 0; i < 4; ++i) {
          int r = lg * 4 + i, cb2 = n * 16 + lr;
          Plds[w][g][r * 64 + (((cb2 >> 3) ^ (r & 7)) << 3) + (cb2 & 7)] =
              (bf16_t)sf[g][n][i];
        }
    }
    __builtin_amdgcn_s_setprio(1);
#pragma unroll
    for (int c = 0; c < 2; ++c) {
      bf16x8 pa[2];
#pragma unroll
      for (int g = 0; g < 2; ++g)
        pa[g] = *(const bf16x8*)&Plds[w][g][lr * 64 +
                                            (((c * 4 + lg) ^ (lr & 7)) << 3)];
#pragma unroll
      for (int nf = 0; nf < 16; ++nf) {
        const int R = nf * 16 + lr;
        bf16x8 vb = *(const bf16x8*)&Vlds[buf][R * 64 +
                                               (((c * 4 + lg) ^ (lr & 7)) << 3)];
        acc[0][nf] = mfma16(pa[0], vb, acc[0][nf]);
        acc[1][nf] = mfma16(pa[1], vb, acc[1][nf]);
      }
    }
    __builtin_amdgcn_s_setprio(0);
  }
#pragma unroll
  for (int g = 0; g < 2; ++g) {
    float rcp[4];
#pragma unroll
    for (int i = 0; i < 4; ++i) {
      float l = l0[g][i];
#pragma unroll
      for (int off = 1; off < 16; off <<= 1) l += __shfl_xor(l, off);
      rcp[i] = 1.f / l;
    }
#pragma unroll
    for (int nf = 0; nf < 16; ++nf)
#pragma unroll
      for (int i = 0; i < 4; ++i)
        o[(size_t)(b * S + qr[g][i]) * ldo + h * 256 + nf * 16 + lr] =
            (bf16_t)(acc[g][nf][i] * rcp[i]);
  }
}

// ---------------------------------------------------------------------------
extern "C" void kernel_launch(void* const* d_in, const int* in_sizes, int n_in,
                              void* d_out, int out_size, void* d_ws,
                              size_t ws_size, hipStream_t stream) {
  const int* xs = (const int*)d_in[0];
  const float* emb = (const float*)d_in[1];
  const float* Wq_l = (const float*)d_in[2];
  const float* Wk_l = (const float*)d_in[3];
  const float* Wv_l = (const float*)d_in[4];
  const float* Wo_l = (const float*)d_in[5];
  const float* bias_l = (const float*)d_in[6];
  const float* Wq_g = (const float*)d_in[7];
  const float* Wk_g = (const float*)d_in[8];
  const float* Wv_g = (const float*)d_in[9];
  const float* Wo_g = (const float*)d_in[10];
  const float* bias_g = (const float*)d_in[11];
  const float* Wq_p = (const float*)d_in[12];
  const float* Wk_p = (const float*)d_in[13];
  const float* Wv_p = (const float*)d_in[14];
  const float* Wo_p = (const float*)d_in[15];
  const float* bias_p = (const float*)d_in[16];
  const float* W_out = (const float*)d_in[17];
  const float* b_out = (const float*)d_in[18];

  char* ws = (char*)d_ws;
  size_t off = 0;
  auto alloc = [&](size_t bytes) -> char* {
    char* p = ws + off;
    off = (off + bytes + 255) & ~(size_t)255;
    return p;
  };
  bf16_t* wqkv_l = (bf16_t*)alloc((size_t)3072 * 256 * 2);
  bf16_t* wqkv_g = (bf16_t*)alloc((size_t)3072 * 256 * 2);
  bf16_t* wqkv_p = (bf16_t*)alloc((size_t)3072 * 512 * 2);
  bf16_t* wo_l_t = (bf16_t*)alloc((size_t)256 * 2048 * 2);
  bf16_t* wo_g_t = (bf16_t*)alloc((size_t)256 * 2048 * 2);
  bf16_t* wo_p_t = (bf16_t*)alloc((size_t)256 * 2048 * 2);
  bf16_t* w_out_t = (bf16_t*)alloc((size_t)240 * 256 * 2);
  bf16_t* xb = (bf16_t*)alloc((size_t)8192 * 256 * 2);
  bf16_t* qkv = (bf16_t*)alloc((size_t)8192 * 3072 * 2);
  bf16_t* vtb = (bf16_t*)alloc((size_t)8192 * 2048 * 2);
  bf16_t* h2 = (bf16_t*)alloc((size_t)8192 * 512 * 2);
  bf16_t* h3 = (bf16_t*)alloc((size_t)8192 * 256 * 2);

  if (off > ws_size) {
    sentinel_k<<<1, 1, 0, stream>>>((float*)d_out);
    return;
  }

  WPack wp;
  wp.e[0] = {Wq_l, wqkv_l, 256, 512};
  wp.e[1] = {Wk_l, wqkv_l + 512 * 256, 256, 512};
  wp.e[2] = {Wv_l, wqkv_l + 1024 * 256, 256, 2048};
  wp.e[3] = {Wq_g, wqkv_g, 256, 512};
  wp.e[4] = {Wk_g, wqkv_g + 512 * 256, 256, 512};
  wp.e[5] = {Wv_g, wqkv_g + 1024 * 256, 256, 2048};
  wp.e[6] = {Wq_p, wqkv_p, 512, 512};
  wp.e[7] = {Wk_p, wqkv_p + 512 * 512, 512, 512};
  wp.e[8] = {Wv_p, wqkv_p + 1024 * 512, 512, 2048};
  wp.e[9] = {Wo_l, wo_l_t, 2048, 256};
  wp.e[10] = {Wo_g, wo_g_t, 2048, 256};
  wp.e[11] = {Wo_p, wo_p_t, 2048, 256};
  wp.e[12] = {W_out, w_out_t, 256, 240};
  prep_all<<<dim3(512, 14), 256, 0, stream>>>(wp, xs, emb, xb);

  auto gemm_small = [&](const bf16_t* A, int lda, const bf16_t* Bt, int K,
                        int N, void* C, int ldc, const float* bias) {
    dim3 g((N + 127) / 128, 256);
    if (bias)
      gemm_btm<32, true><<<g, 256, 0, stream>>>(A, lda, Bt, K, C, ldc, bias, N);
    else
      gemm_btm<32, false><<<g, 256, 0, stream>>>(A, lda, Bt, K, C, ldc, nullptr, N);
  };

  dim3 qg(24, 64), ag(64, 8), ag4(64, 4);
  // ---- local layer ----
  gemm_bt<false, true><<<qg, 256, 0, stream>>>(xb, 256, wqkv_l, 256, qkv, 3072,
                                               nullptr, 3072, vtb);
  attn_k<0><<<ag, 512, 0, stream>>>(qkv, vtb, bias_l, qkv + 1024, 3072, 3072);
  gemm_small(qkv + 1024, 3072, wo_l_t, 2048, 256, h2, 512, nullptr);
  // ---- global layer (QBLK=256) ----
  gemm_bt<false, true><<<qg, 256, 0, stream>>>(xb, 256, wqkv_g, 256, qkv, 3072,
                                               nullptr, 3072, vtb);
  attn_g256<<<ag4, 512, 0, stream>>>(qkv, vtb, bias_g, qkv + 1024, 3072, 3072);
  gemm_small(qkv + 1024, 3072, wo_g_t, 2048, 256, h2 + 256, 512, nullptr);
  // ---- predictive (causal) layer on h2 [8192,512] ----
  gemm_bt<false, true><<<qg, 256, 0, stream>>>(h2, 512, wqkv_p, 512, qkv, 3072,
                                               nullptr, 3072, vtb);
  attn_k<2><<<ag, 512, 0, stream>>>(qkv, vtb, bias_p, qkv + 1024, 3072, 3072);
  gemm_small(qkv + 1024, 3072, wo_p_t, 2048, 256, h3, 256, nullptr);
  // ---- head ----
  gemm_small(h3, 256, w_out_t, 256, 240, (float*)d_out, 240, b_out);
}

// Round 17
// 364.612 us; speedup vs baseline: 1.0632x; 1.0311x over previous
//
#include <hip/hip_runtime.h>
#include <hip/hip_bf16.h>

// ---------------------------------------------------------------------------
// Model: B=8 S=1024 D=256 H=8 DK=64 DV=256; LB=LF=32, CUT=128, VOCAB=240
// R16 config + LDS-tiled (coalesced) weight transpose-cast in prep_all.
// ---------------------------------------------------------------------------

typedef __bf16 bf16_t;
typedef __bf16 bf16x4 __attribute__((ext_vector_type(4)));
typedef __bf16 bf16x8 __attribute__((ext_vector_type(8)));
typedef float f32x4 __attribute__((ext_vector_type(4)));

__device__ __forceinline__ f32x4 mfma16(bf16x8 a, bf16x8 b, f32x4 c) {
  return __builtin_amdgcn_mfma_f32_16x16x32_bf16(a, b, c, 0, 0, 0);
}

#define GLL16(GP, LP)                                                          \
  __builtin_amdgcn_global_load_lds(                                            \
      (const __attribute__((address_space(1))) void*)(GP),                     \
      (__attribute__((address_space(3))) void*)(LP), 16, 0, 0)

__device__ __forceinline__ int imin(int a, int b) { return a < b ? a : b; }
__device__ __forceinline__ int imax(int a, int b) { return a > b ? a : b; }

// ---- weight transpose+cast (LDS-tiled, both sides coalesced) + embedding ---
struct WEnt { const float* src; bf16_t* dst; int K; int N; };
struct WPack { WEnt e[13]; };

__global__ void prep_all(WPack p, const int* __restrict__ xs,
                         const float* __restrict__ emb,
                         bf16_t* __restrict__ xb) {
  if (blockIdx.y == 13) {  // embedding gather (coalesced)
    for (int id = blockIdx.x * 256 + threadIdx.x; id < 8192 * 256;
         id += gridDim.x * 256) {
      int row = id >> 8, d = id & 255;
      xb[id] = (bf16_t)emb[(size_t)xs[row] * 256 + d];
    }
    return;
  }
  const WEnt E = p.e[blockIdx.y];
  const int tk = E.K >> 6;             // K always multiple of 64
  const int tn = (E.N + 63) >> 6;
  const int tot = tk * tn;
  __shared__ float t[64][65];
  const int tid = threadIdx.x;
  const int sub = tid >> 6;            // wave id 0..3
  const int ln = tid & 63;
  for (int tile = blockIdx.x; tile < tot; tile += gridDim.x) {
    const int k0 = (tile % tk) << 6;
    const int n0 = (tile / tk) << 6;
    // read W[k0+r][n0+c], coalesced over c
#pragma unroll
    for (int it = 0; it < 16; ++it) {
      int r = it * 4 + sub, c = ln;
      if (n0 + c < E.N) t[r][c] = E.src[(size_t)(k0 + r) * E.N + n0 + c];
    }
    __syncthreads();
    // write Wt[n0+c][k0+r], coalesced over r
#pragma unroll
    for (int it = 0; it < 16; ++it) {
      int c = it * 4 + sub, r = ln;
      if (n0 + c < E.N)
        E.dst[(size_t)(n0 + c) * E.K + k0 + r] = (bf16_t)t[r][c];
    }
    __syncthreads();
  }
}

__global__ void sentinel_k(float* out) { out[0] = 1.0e6f; }

// ---- GEMM 128x128, 2-phase dbuf: C = A[M,K] * Bt[N,K]^T --------------------
template <bool F32OUT, bool VT>
__global__ __launch_bounds__(256) void gemm_bt(
    const bf16_t* __restrict__ A, int lda, const bf16_t* __restrict__ Bt, int K,
    void* __restrict__ Cv, int ldc, const float* __restrict__ bias, int N,
    bf16_t* __restrict__ vt) {
  __shared__ bf16_t As[2][128 * 32];
  __shared__ bf16_t Bs[2][128 * 32];
  const int tid = threadIdx.x;
  const int lane = tid & 63, wave = tid >> 6;
  const int wr = wave >> 1, wc = wave & 1;
  const int lr = lane & 15, lg = lane >> 4;
  const int bm = blockIdx.y, bn = blockIdx.x;

  const int ar = tid >> 2;
  const int ac = (tid & 3) * 8;
  const bf16_t* a0 = A + (size_t)(bm * 128 + ar) * lda + ac;
  const bf16_t* a1 = A + (size_t)(bm * 128 + 64 + ar) * lda + ac;
  int br0 = imin(bn * 128 + ar, N - 1);
  int br1 = imin(bn * 128 + 64 + ar, N - 1);
  const bf16_t* b0 = Bt + (size_t)br0 * K + ac;
  const bf16_t* b1 = Bt + (size_t)br1 * K + ac;

  f32x4 acc[4][4] = {};
  const int nk = K >> 5;

  auto STAGE = [&](int kt, int bs) {
    const int ko = kt * 32;
    GLL16(a0 + ko, &As[bs][wave * 512]);
    GLL16(a1 + ko, &As[bs][2048 + wave * 512]);
    GLL16(b0 + ko, &Bs[bs][wave * 512]);
    GLL16(b1 + ko, &Bs[bs][2048 + wave * 512]);
  };

  STAGE(0, 0);
  asm volatile("s_waitcnt vmcnt(0)" ::: "memory");
  __syncthreads();
  int cur = 0;
  for (int kt = 0; kt < nk; ++kt) {
    const bool pf = (kt + 1 < nk);
    if (pf) STAGE(kt + 1, cur ^ 1);
    bf16x8 af[4], bfv[4];
#pragma unroll
    for (int m = 0; m < 4; ++m)
      af[m] = *(const bf16x8*)&As[cur][(wr * 64 + m * 16 + lr) * 32 + lg * 8];
#pragma unroll
    for (int n = 0; n < 4; ++n)
      bfv[n] = *(const bf16x8*)&Bs[cur][(wc * 64 + n * 16 + lr) * 32 + lg * 8];
    __builtin_amdgcn_s_setprio(1);
#pragma unroll
    for (int m = 0; m < 4; ++m)
#pragma unroll
      for (int n = 0; n < 4; ++n) acc[m][n] = mfma16(af[m], bfv[n], acc[m][n]);
    __builtin_amdgcn_s_setprio(0);
    if (pf) {
      asm volatile("s_waitcnt vmcnt(0)" ::: "memory");
      __syncthreads();
      cur ^= 1;
    }
  }
  const int r0 = bm * 128 + wr * 64;
  const int c0 = bn * 128 + wc * 64;
  if (VT && c0 >= 1024) {
    const int bq = r0 >> 10;
    const int s0 = r0 & 1023;
#pragma unroll
    for (int m = 0; m < 4; ++m)
#pragma unroll
      for (int n = 0; n < 4; ++n) {
        int c = c0 + n * 16 + lr;
        bf16x4 pk;
#pragma unroll
        for (int i = 0; i < 4; ++i) pk[i] = (bf16_t)acc[m][n][i];
        *(bf16x4*)(vt + (size_t)(bq * 2048 + (c - 1024)) * 1024 + s0 + m * 16 +
                   lg * 4) = pk;
      }
  } else {
#pragma unroll
    for (int m = 0; m < 4; ++m)
#pragma unroll
      for (int n = 0; n < 4; ++n) {
        int c = c0 + n * 16 + lr;
        if (c >= N) continue;
#pragma unroll
        for (int i = 0; i < 4; ++i) {
          int r = r0 + m * 16 + lg * 4 + i;
          if (F32OUT)
            ((float*)Cv)[(size_t)r * ldc + c] = acc[m][n][i] + bias[c];
          else
            ((bf16_t*)Cv)[(size_t)r * ldc + c] = (bf16_t)acc[m][n][i];
        }
      }
  }
}

// ---- GEMM BMx128, 2-phase dbuf, swapped operands (vectorized epilogue) -----
template <int BM, bool F32OUT>
__global__ __launch_bounds__(256) void gemm_btm(
    const bf16_t* __restrict__ A, int lda, const bf16_t* __restrict__ Bt, int K,
    void* __restrict__ Cv, int ldc, const float* __restrict__ bias, int N) {
  constexpr int MF = BM / 32;
  __shared__ bf16_t As[2][BM * 32];
  __shared__ bf16_t Bs[2][128 * 32];
  const int tid = threadIdx.x;
  const int lane = tid & 63, wave = tid >> 6;
  const int wr = wave >> 1, wc = wave & 1;
  const int lr = lane & 15, lg = lane >> 4;
  const int bm = blockIdx.y, bn = blockIdx.x;

  const int ar = tid >> 2;
  const int ac = (tid & 3) * 8;
  const bf16_t* a0 = A + (size_t)(bm * BM + (BM == 32 ? (ar & 31) : ar)) * lda + ac;
  int br0 = imin(bn * 128 + ar, N - 1);
  int br1 = imin(bn * 128 + 64 + ar, N - 1);
  const bf16_t* b0 = Bt + (size_t)br0 * K + ac;
  const bf16_t* b1 = Bt + (size_t)br1 * K + ac;

  f32x4 acc[MF][4] = {};
  const int nk = K >> 5;

  auto STAGE = [&](int kt, int bs) {
    const int ko = kt * 32;
    if (BM == 64) {
      GLL16(a0 + ko, &As[bs][wave * 512]);
    } else {
      if (wave < 2) GLL16(a0 + ko, &As[bs][wave * 512]);
    }
    GLL16(b0 + ko, &Bs[bs][wave * 512]);
    GLL16(b1 + ko, &Bs[bs][2048 + wave * 512]);
  };

  STAGE(0, 0);
  asm volatile("s_waitcnt vmcnt(0)" ::: "memory");
  __syncthreads();
  int cur = 0;
  for (int kt = 0; kt < nk; ++kt) {
    const bool pf = (kt + 1 < nk);
    if (pf) STAGE(kt + 1, cur ^ 1);
    bf16x8 af[MF], bfv[4];
#pragma unroll
    for (int m = 0; m < MF; ++m)
      af[m] = *(const bf16x8*)&As[cur][(wr * (BM / 2) + m * 16 + lr) * 32 + lg * 8];
#pragma unroll
    for (int n = 0; n < 4; ++n)
      bfv[n] = *(const bf16x8*)&Bs[cur][(wc * 64 + n * 16 + lr) * 32 + lg * 8];
    __builtin_amdgcn_s_setprio(1);
#pragma unroll
    for (int m = 0; m < MF; ++m)
#pragma unroll
      for (int n = 0; n < 4; ++n) acc[m][n] = mfma16(bfv[n], af[m], acc[m][n]);
    __builtin_amdgcn_s_setprio(0);
    if (pf) {
      asm volatile("s_waitcnt vmcnt(0)" ::: "memory");
      __syncthreads();
      cur ^= 1;
    }
  }
  const int r0 = bm * BM + wr * (BM / 2);
  const int c0 = bn * 128 + wc * 64;
#pragma unroll
  for (int m = 0; m < MF; ++m) {
    const int r = r0 + m * 16 + lr;
#pragma unroll
    for (int n = 0; n < 4; ++n) {
      const int c = c0 + n * 16 + lg * 4;
      if (c >= N) continue;
      if (F32OUT) {
        float4 bv = *(const float4*)&bias[c];
        float4 ov = {acc[m][n][0] + bv.x, acc[m][n][1] + bv.y,
                     acc[m][n][2] + bv.z, acc[m][n][3] + bv.w};
        *(float4*)&((float*)Cv)[(size_t)r * ldc + c] = ov;
      } else {
        bf16x4 pk;
#pragma unroll
        for (int i = 0; i < 4; ++i) pk[i] = (bf16_t)acc[m][n][i];
        *(bf16x4*)&((bf16_t*)Cv)[(size_t)r * ldc + c] = pk;
      }
    }
  }
}

// ---- fused flash attention QBLK=128 — LOCAL / CAUSAL (3-deep pipeline) -----
// Counted vmcnt(5) mid-loop + raw s_barrier (never vmcnt(0) mid-loop).
template <int VAR>
__global__ __launch_bounds__(512) void attn_k(
    const bf16_t* __restrict__ qkv, const bf16_t* __restrict__ vt,
    const float* __restrict__ bias, bf16_t* __restrict__ o, int ldqk, int ldo) {
  constexpr int S = 1024, H = 8;
  __shared__ bf16_t Klds[3][64 * 64];
  __shared__ bf16_t Vlds[3][256 * 64];
  __shared__ bf16_t Plds[8][16 * 64];
  __shared__ float blds[260];
  const int tid = threadIdx.x, lane = tid & 63, w = tid >> 6;
  const int lr = lane & 15, lg = lane >> 4;
  const int bh = blockIdx.x;
  const int qt = (VAR == 2) ? (7 - (int)blockIdx.y) : blockIdx.y;  // LPT
  const int b = bh >> 3, h = bh & 7;
  const int TSIZE = (VAR == 0) ? 65 : 257;
  for (int t = tid; t < TSIZE; t += 512) blds[t] = bias[t * H + h];
  const int qb0 = qt * 128;
#define QROW(j) (VAR == 2 ? qb0 + (j) * 8 + w : qb0 + w * 16 + (j))
  const size_t qoff = (size_t)(b * S + QROW(lr)) * ldqk + h * 64;
  bf16x8 qf0 = *(const bf16x8*)(qkv + qoff + lg * 8);
  bf16x8 qf1 = *(const bf16x8*)(qkv + qoff + 32 + lg * 8);
  int qr[4];
#pragma unroll
  for (int i = 0; i < 4; ++i) qr[i] = QROW(lg * 4 + i);

  f32x4 acc[16] = {};
  float m0[4], l0[4];
#pragma unroll
  for (int i = 0; i < 4; ++i) { m0[i] = -__builtin_inff(); l0[i] = 0.f; }
  int kt0 = 0, kt1 = 15;
  if (VAR == 0) {
    kt0 = imax(0, (qb0 - 32) >> 6);
    kt1 = imin(15, (qb0 + 127 + 32) >> 6);
  }
  if (VAR == 2) kt1 = 2 * qt + 1;

  const int sr = tid >> 3, sj = tid & 7;
  const int ksw = (sj ^ (sr & 7)) << 3;
  const bf16_t* kbase = qkv + 512 + (size_t)(b * S + sr) * ldqk + h * 64 + ksw;
  const bf16_t* vbase = vt + (size_t)((b * H + h) * 256 + sr) * 1024 + ksw;
  bf16_t* Pw = &Plds[w][0];

  auto STAGE = [&](int kt, int bs) {
    GLL16(kbase + (size_t)(kt * 64) * ldqk, &Klds[bs][w * 512]);
#pragma unroll
    for (int qq = 0; qq < 4; ++qq)
      GLL16(vbase + (size_t)(qq * 64) * 1024 + kt * 64,
            &Vlds[bs][qq * 4096 + w * 512]);
  };

  STAGE(kt0, 0);
  if (kt0 + 1 <= kt1) STAGE(kt0 + 1, 1);

  for (int kt = kt0; kt <= kt1; ++kt) {
    const int buf = (kt - kt0) % 3;
    if (kt < kt1) {
      asm volatile("s_waitcnt vmcnt(5)" ::: "memory");
    } else {
      asm volatile("s_waitcnt vmcnt(0)" ::: "memory");
    }
    __builtin_amdgcn_s_barrier();
    if (kt + 2 <= kt1) STAGE(kt + 2, (kt + 2 - kt0) % 3);

    const int kvlo = kt * 64;
    bool active = true;
    if (VAR == 0) {
      int q0w = qb0 + w * 16;
      active = (kvlo + 63 >= q0w - 32) && (kvlo <= q0w + 47);
    }
    if (VAR == 2) active = (kvlo <= qb0 + 120 + w);
    if (active) {
      f32x4 sf[4];
      __builtin_amdgcn_s_setprio(1);
#pragma unroll
      for (int n = 0; n < 4; ++n) {
        const int R = n * 16 + lr, rs = lr & 7;
        bf16x8 kb0 = *(const bf16x8*)&Klds[buf][R * 64 + ((lg ^ rs) << 3)];
        bf16x8 kb1 = *(const bf16x8*)&Klds[buf][R * 64 + (((4 + lg) ^ rs) << 3)];
        f32x4 z = {0.f, 0.f, 0.f, 0.f};
        z = mfma16(qf0, kb0, z);
        z = mfma16(qf1, kb1, z);
        sf[n] = z;
      }
      __builtin_amdgcn_s_setprio(0);
      bool sat = false;
      float cb = 0.f;
      if (VAR == 2) {
        if (kvlo + 63 <= qb0 - 128) { sat = true; cb = blds[0]; }
      }
      float tmL[4];
#pragma unroll
      for (int i = 0; i < 4; ++i) tmL[i] = -__builtin_inff();
      if (sat) {
#pragma unroll
        for (int n = 0; n < 4; ++n)
#pragma unroll
          for (int i = 0; i < 4; ++i) {
            float val = sf[n][i] * 0.125f + cb;
            sf[n][i] = val;
            tmL[i] = fmaxf(tmL[i], val);
          }
      } else {
#pragma unroll
        for (int n = 0; n < 4; ++n) {
          int kv = kvlo + n * 16 + lr;
#pragma unroll
          for (int i = 0; i < 4; ++i) {
            int rel = kv - qr[i];
            float val;
            if (VAR == 0) {
              val = (rel >= -32 && rel <= 32)
                        ? sf[n][i] * 0.125f + blds[rel + 32] : -1e9f;
            } else {
              int idx = imax(rel, -128) + 128;
              val = (rel <= 0) ? sf[n][i] * 0.125f + blds[idx] : -1e9f;
            }
            sf[n][i] = val;
            tmL[i] = fmaxf(tmL[i], val);
          }
        }
      }
      bool need = false;
#pragma unroll
      for (int i = 0; i < 4; ++i) need |= (tmL[i] > m0[i] + 8.0f);
      if (__any(need ? 1 : 0)) {
        float corr[4];
#pragma unroll
        for (int i = 0; i < 4; ++i) {
          float tm = tmL[i];
#pragma unroll
          for (int off = 1; off < 16; off <<= 1)
            tm = fmaxf(tm, __shfl_xor(tm, off));
          float nm = fmaxf(m0[i], tm);
          corr[i] = __expf(m0[i] - nm);
          m0[i] = nm;
          l0[i] *= corr[i];
        }
        f32x4 cv = {corr[0], corr[1], corr[2], corr[3]};
#pragma unroll
        for (int nf = 0; nf < 16; ++nf) acc[nf] *= cv;
      }
#pragma unroll
      for (int n = 0; n < 4; ++n)
#pragma unroll
        for (int i = 0; i < 4; ++i) {
          float p = __expf(sf[n][i] - m0[i]);
          sf[n][i] = p;
          l0[i] += p;
        }
#pragma unroll
      for (int n = 0; n < 4; ++n)
#pragma unroll
        for (int i = 0; i < 4; ++i) {
          int r = lg * 4 + i, cb2 = n * 16 + lr;
          Pw[r * 64 + (((cb2 >> 3) ^ (r & 7)) << 3) + (cb2 & 7)] =
              (bf16_t)sf[n][i];
        }
      __builtin_amdgcn_s_setprio(1);
#pragma unroll
      for (int c = 0; c < 2; ++c) {
        bf16x8 pa = *(const bf16x8*)&Pw[lr * 64 + (((c * 4 + lg) ^ (lr & 7)) << 3)];
#pragma unroll
        for (int nf = 0; nf < 16; ++nf) {
          const int R = nf * 16 + lr;
          bf16x8 vb = *(const bf16x8*)&Vlds[buf][R * 64 + (((c * 4 + lg) ^ (lr & 7)) << 3)];
          acc[nf] = mfma16(pa, vb, acc[nf]);
        }
      }
      __builtin_amdgcn_s_setprio(0);
    }
  }
  float rcp[4];
#pragma unroll
  for (int i = 0; i < 4; ++i) {
    float l = l0[i];
#pragma unroll
    for (int off = 1; off < 16; off <<= 1) l += __shfl_xor(l, off);
    rcp[i] = 1.f / l;
  }
#pragma unroll
  for (int nf = 0; nf < 16; ++nf)
#pragma unroll
    for (int i = 0; i < 4; ++i)
      o[(size_t)(b * S + qr[i]) * ldo + h * 256 + nf * 16 + lr] =
          (bf16_t)(acc[nf][i] * rcp[i]);
#undef QROW
}

// ---- fused flash attention QBLK=256 — GLOBAL (3-deep pipeline) -------------
__global__ __launch_bounds__(512) void attn_g256(
    const bf16_t* __restrict__ qkv, const bf16_t* __restrict__ vt,
    const float* __restrict__ bias, bf16_t* __restrict__ o, int ldqk, int ldo) {
  constexpr int S = 1024, H = 8;
  __shared__ bf16_t Klds[3][64 * 64];
  __shared__ bf16_t Vlds[3][256 * 64];
  __shared__ bf16_t Plds[8][2][16 * 64];
  __shared__ float blds[260];
  const int tid = threadIdx.x, lane = tid & 63, w = tid >> 6;
  const int lr = lane & 15, lg = lane >> 4;
  const int bh = blockIdx.x, qt = blockIdx.y;
  const int b = bh >> 3, h = bh & 7;
  for (int t = tid; t < 257; t += 512) blds[t] = bias[t * H + h];
  const int qb0 = qt * 256;
  bf16x8 qf0[2], qf1[2];
  int qr[2][4];
#pragma unroll
  for (int g = 0; g < 2; ++g) {
    const size_t qoff =
        (size_t)(b * S + qb0 + w * 32 + g * 16 + lr) * ldqk + h * 64;
    qf0[g] = *(const bf16x8*)(qkv + qoff + lg * 8);
    qf1[g] = *(const bf16x8*)(qkv + qoff + 32 + lg * 8);
#pragma unroll
    for (int i = 0; i < 4; ++i) qr[g][i] = qb0 + w * 32 + g * 16 + lg * 4 + i;
  }

  f32x4 acc[2][16] = {};
  float m0[2][4], l0[2][4];
#pragma unroll
  for (int g = 0; g < 2; ++g)
#pragma unroll
    for (int i = 0; i < 4; ++i) { m0[g][i] = -__builtin_inff(); l0[g][i] = 0.f; }

  const int sr = tid >> 3, sj = tid & 7;
  const int ksw = (sj ^ (sr & 7)) << 3;
  const bf16_t* kbase = qkv + 512 + (size_t)(b * S + sr) * ldqk + h * 64 + ksw;
  const bf16_t* vbase = vt + (size_t)((b * H + h) * 256 + sr) * 1024 + ksw;

  auto STAGE = [&](int kt, int bs) {
    GLL16(kbase + (size_t)(kt * 64) * ldqk, &Klds[bs][w * 512]);
#pragma unroll
    for (int qq = 0; qq < 4; ++qq)
      GLL16(vbase + (size_t)(qq * 64) * 1024 + kt * 64,
            &Vlds[bs][qq * 4096 + w * 512]);
  };

  STAGE(0, 0);
  STAGE(1, 1);

  for (int kt = 0; kt <= 15; ++kt) {
    const int buf = kt % 3;
    if (kt < 15) {
      asm volatile("s_waitcnt vmcnt(5)" ::: "memory");
    } else {
      asm volatile("s_waitcnt vmcnt(0)" ::: "memory");
    }
    __builtin_amdgcn_s_barrier();
    if (kt + 2 <= 15) STAGE(kt + 2, (kt + 2) % 3);

    const int kvlo = kt * 64;
    f32x4 sf[2][4];
    __builtin_amdgcn_s_setprio(1);
#pragma unroll
    for (int n = 0; n < 4; ++n) {
      const int R = n * 16 + lr, rs = lr & 7;
      bf16x8 kb0 = *(const bf16x8*)&Klds[buf][R * 64 + ((lg ^ rs) << 3)];
      bf16x8 kb1 = *(const bf16x8*)&Klds[buf][R * 64 + (((4 + lg) ^ rs) << 3)];
#pragma unroll
      for (int g = 0; g < 2; ++g) {
        f32x4 z = {0.f, 0.f, 0.f, 0.f};
        z = mfma16(qf0[g], kb0, z);
        z = mfma16(qf1[g], kb1, z);
        sf[g][n] = z;
      }
    }
    __builtin_amdgcn_s_setprio(0);
    bool sat = false;
    float cb = 0.f;
    if (kvlo + 63 <= qb0 - 128) { sat = true; cb = blds[0]; }
    else if (kvlo >= qb0 + 384) { sat = true; cb = blds[256]; }
    float tmL[2][4];
#pragma unroll
    for (int g = 0; g < 2; ++g)
#pragma unroll
      for (int i = 0; i < 4; ++i) tmL[g][i] = -__builtin_inff();
    if (sat) {
#pragma unroll
      for (int g = 0; g < 2; ++g)
#pragma unroll
        for (int n = 0; n < 4; ++n)
#pragma unroll
          for (int i = 0; i < 4; ++i) {
            float val = sf[g][n][i] * 0.125f + cb;
            sf[g][n][i] = val;
            tmL[g][i] = fmaxf(tmL[g][i], val);
          }
    } else {
#pragma unroll
      for (int n = 0; n < 4; ++n) {
        int kv = kvlo + n * 16 + lr;
#pragma unroll
        for (int g = 0; g < 2; ++g)
#pragma unroll
          for (int i = 0; i < 4; ++i) {
            int rel = kv - qr[g][i];
            int idx = imin(imax(rel, -128), 128) + 128;
            float val = sf[g][n][i] * 0.125f + blds[idx];
            sf[g][n][i] = val;
            tmL[g][i] = fmaxf(tmL[g][i], val);
          }
      }
    }
#pragma unroll
    for (int g = 0; g < 2; ++g) {
      bool need = false;
#pragma unroll
      for (int i = 0; i < 4; ++i) need |= (tmL[g][i] > m0[g][i] + 8.0f);
      if (__any(need ? 1 : 0)) {
        float corr[4];
#pragma unroll
        for (int i = 0; i < 4; ++i) {
          float tm = tmL[g][i];
#pragma unroll
          for (int off = 1; off < 16; off <<= 1)
            tm = fmaxf(tm, __shfl_xor(tm, off));
          float nm = fmaxf(m0[g][i], tm);
          corr[i] = __expf(m0[g][i] - nm);
          m0[g][i] = nm;
          l0[g][i] *= corr[i];
        }
        f32x4 cv = {corr[0], corr[1], corr[2], corr[3]};
#pragma unroll
        for (int nf = 0; nf < 16; ++nf) acc[g][nf] *= cv;
      }
#pragma unroll
      for (int n = 0; n < 4; ++n)
#pragma unroll
        for (int i = 0; i < 4; ++i) {
          float p = __expf(sf[g][n][i] - m0[g][i]);
          sf[g][n][i] = p;
          l0[g][i] += p;
        }
#pragma unroll
      for (int n = 0; n < 4; ++n)
#pragma unroll
        for (int i = 0; i < 4; ++i) {
          int r = lg * 4 + i, cb2 = n * 16 + lr;
          Plds[w][g][r * 64 + (((cb2 >> 3) ^ (r & 7)) << 3) + (cb2 & 7)] =
              (bf16_t)sf[g][n][i];
        }
    }
    __builtin_amdgcn_s_setprio(1);
#pragma unroll
    for (int c = 0; c < 2; ++c) {
      bf16x8 pa[2];
#pragma unroll
      for (int g = 0; g < 2; ++g)
        pa[g] = *(const bf16x8*)&Plds[w][g][lr * 64 +
                                            (((c * 4 + lg) ^ (lr & 7)) << 3)];
#pragma unroll
      for (int nf = 0; nf < 16; ++nf) {
        const int R = nf * 16 + lr;
        bf16x8 vb = *(const bf16x8*)&Vlds[buf][R * 64 +
                                               (((c * 4 + lg) ^ (lr & 7)) << 3)];
        acc[0][nf] = mfma16(pa[0], vb, acc[0][nf]);
        acc[1][nf] = mfma16(pa[1], vb, acc[1][nf]);
      }
    }
    __builtin_amdgcn_s_setprio(0);
  }
#pragma unroll
  for (int g = 0; g < 2; ++g) {
    float rcp[4];
#pragma unroll
    for (int i = 0; i < 4; ++i) {
      float l = l0[g][i];
#pragma unroll
      for (int off = 1; off < 16; off <<= 1) l += __shfl_xor(l, off);
      rcp[i] = 1.f / l;
    }
#pragma unroll
    for (int nf = 0; nf < 16; ++nf)
#pragma unroll
      for (int i = 0; i < 4; ++i)
        o[(size_t)(b * S + qr[g][i]) * ldo + h * 256 + nf * 16 + lr] =
            (bf16_t)(acc[g][nf][i] * rcp[i]);
  }
}

// ---------------------------------------------------------------------------
extern "C" void kernel_launch(void* const* d_in, const int* in_sizes, int n_in,
                              void* d_out, int out_size, void* d_ws,
                              size_t ws_size, hipStream_t stream) {
  const int* xs = (const int*)d_in[0];
  const float* emb = (const float*)d_in[1];
  const float* Wq_l = (const float*)d_in[2];
  const float* Wk_l = (const float*)d_in[3];
  const float* Wv_l = (const float*)d_in[4];
  const float* Wo_l = (const float*)d_in[5];
  const float* bias_l = (const float*)d_in[6];
  const float* Wq_g = (const float*)d_in[7];
  const float* Wk_g = (const float*)d_in[8];
  const float* Wv_g = (const float*)d_in[9];
  const float* Wo_g = (const float*)d_in[10];
  const float* bias_g = (const float*)d_in[11];
  const float* Wq_p = (const float*)d_in[12];
  const float* Wk_p = (const float*)d_in[13];
  const float* Wv_p = (const float*)d_in[14];
  const float* Wo_p = (const float*)d_in[15];
  const float* bias_p = (const float*)d_in[16];
  const float* W_out = (const float*)d_in[17];
  const float* b_out = (const float*)d_in[18];

  char* ws = (char*)d_ws;
  size_t off = 0;
  auto alloc = [&](size_t bytes) -> char* {
    char* p = ws + off;
    off = (off + bytes + 255) & ~(size_t)255;
    return p;
  };
  bf16_t* wqkv_l = (bf16_t*)alloc((size_t)3072 * 256 * 2);
  bf16_t* wqkv_g = (bf16_t*)alloc((size_t)3072 * 256 * 2);
  bf16_t* wqkv_p = (bf16_t*)alloc((size_t)3072 * 512 * 2);
  bf16_t* wo_l_t = (bf16_t*)alloc((size_t)256 * 2048 * 2);
  bf16_t* wo_g_t = (bf16_t*)alloc((size_t)256 * 2048 * 2);
  bf16_t* wo_p_t = (bf16_t*)alloc((size_t)256 * 2048 * 2);
  bf16_t* w_out_t = (bf16_t*)alloc((size_t)240 * 256 * 2);
  bf16_t* xb = (bf16_t*)alloc((size_t)8192 * 256 * 2);
  bf16_t* qkv = (bf16_t*)alloc((size_t)8192 * 3072 * 2);
  bf16_t* vtb = (bf16_t*)alloc((size_t)8192 * 2048 * 2);
  bf16_t* h2 = (bf16_t*)alloc((size_t)8192 * 512 * 2);
  bf16_t* h3 = (bf16_t*)alloc((size_t)8192 * 256 * 2);

  if (off > ws_size) {
    sentinel_k<<<1, 1, 0, stream>>>((float*)d_out);
    return;
  }

  WPack wp;
  wp.e[0] = {Wq_l, wqkv_l, 256, 512};
  wp.e[1] = {Wk_l, wqkv_l + 512 * 256, 256, 512};
  wp.e[2] = {Wv_l, wqkv_l + 1024 * 256, 256, 2048};
  wp.e[3] = {Wq_g, wqkv_g, 256, 512};
  wp.e[4] = {Wk_g, wqkv_g + 512 * 256, 256, 512};
  wp.e[5] = {Wv_g, wqkv_g + 1024 * 256, 256, 2048};
  wp.e[6] = {Wq_p, wqkv_p, 512, 512};
  wp.e[7] = {Wk_p, wqkv_p + 512 * 512, 512, 512};
  wp.e[8] = {Wv_p, wqkv_p + 1024 * 512, 512, 2048};
  wp.e[9] = {Wo_l, wo_l_t, 2048, 256};
  wp.e[10] = {Wo_g, wo_g_t, 2048, 256};
  wp.e[11] = {Wo_p, wo_p_t, 2048, 256};
  wp.e[12] = {W_out, w_out_t, 256, 240};
  prep_all<<<dim3(256, 14), 256, 0, stream>>>(wp, xs, emb, xb);

  auto gemm_small = [&](const bf16_t* A, int lda, const bf16_t* Bt, int K,
                        int N, void* C, int ldc, const float* bias) {
    dim3 g((N + 127) / 128, 256);
    if (bias)
      gemm_btm<32, true><<<g, 256, 0, stream>>>(A, lda, Bt, K, C, ldc, bias, N);
    else
      gemm_btm<32, false><<<g, 256, 0, stream>>>(A, lda, Bt, K, C, ldc, nullptr, N);
  };

  dim3 qg(24, 64), ag(64, 8), ag4(64, 4);
  // ---- local layer ----
  gemm_bt<false, true><<<qg, 256, 0, stream>>>(xb, 256, wqkv_l, 256, qkv, 3072,
                                               nullptr, 3072, vtb);
  attn_k<0><<<ag, 512, 0, stream>>>(qkv, vtb, bias_l, qkv + 1024, 3072, 3072);
  gemm_small(qkv + 1024, 3072, wo_l_t, 2048, 256, h2, 512, nullptr);
  // ---- global layer (QBLK=256) ----
  gemm_bt<false, true><<<qg, 256, 0, stream>>>(xb, 256, wqkv_g, 256, qkv, 3072,
                                               nullptr, 3072, vtb);
  attn_g256<<<ag4, 512, 0, stream>>>(qkv, vtb, bias_g, qkv + 1024, 3072, 3072);
  gemm_small(qkv + 1024, 3072, wo_g_t, 2048, 256, h2 + 256, 512, nullptr);
  // ---- predictive (causal) layer on h2 [8192,512] ----
  gemm_bt<false, true><<<qg, 256, 0, stream>>>(h2, 512, wqkv_p, 512, qkv, 3072,
                                               nullptr, 3072, vtb);
  attn_k<2><<<ag, 512, 0, stream>>>(qkv, vtb, bias_p, qkv + 1024, 3072, 3072);
  gemm_small(qkv + 1024, 3072, wo_p_t, 2048, 256, h3, 256, nullptr);
  // ---- head ----
  gemm_small(h3, 256, w_out_t, 256, 240, (float*)d_out, 240, b_out);
}